// Round 12
// baseline (969.710 us; speedup 1.0000x reference)
//
#include <hip/hip_runtime.h>

#define HD 128
#define LD 2048
#define BD 64
#define VD 32000
#define NSTEP 2047   // L-1 scan steps, t = 0..2046

// f32 constants exactly matching the reference's f32-cast scalars
#define C_ALPHA  0.05f
#define C_THMIN  0.4f
#define C_THSPAN 1.1f
#define C_NEPS   1e-12f
#define C_LNEPS  1e-5f

// ---------------------------------------------------------------------------
// K1: fused embed-gather + MLP + LayerNorm + keys=hn@kp  (unchanged)
// Only tokens >= 896 are live (first possible fire is t=931).
// ---------------------------------------------------------------------------
#define HSP 132
#define W1P 68
#define W2P 132
#define ATP 68
#define TOK0 896
#define TBLK 9

extern "C" __global__ __launch_bounds__(256, 1)
void k_tokens(const int* __restrict__ seq, const float* __restrict__ embed,
              const float* __restrict__ w1, const float* __restrict__ b1,
              const float* __restrict__ w2, const float* __restrict__ b2,
              const float* __restrict__ lng, const float* __restrict__ lnb,
              const float* __restrict__ kp, float* __restrict__ keys)
{
  extern __shared__ float sm[];
  float* hs = sm;
  float* wt = sm + 128*HSP;
  float* at = wt + 128*W1P;
  const int tid = threadIdx.x;
  const int bb  = blockIdx.x / TBLK;
  const int rel = blockIdx.x % TBLK;
  const long long tokBase = (long long)bb * LD + TOK0 + rel * 128;

  for (int u = tid; u < 128*32; u += 256) {
    const int tok = u >> 5, seg = u & 31;
    const int s = seq[tokBase + tok];
    *(float4*)(hs + tok*HSP + seg*4) =
        *(const float4*)(embed + (long long)s*HD + seg*4);
  }
  __syncthreads();

  const int tg = tid >> 4;
  const int ig = tid & 15;

  float xacc[8][8] = {};

  for (int jt = 0; jt < 4; ++jt) {
    for (int u = tid; u < 128*16; u += 256) {
      const int i = u >> 4, q = u & 15;
      *(float4*)(wt + i*W1P + q*4) =
          *(const float4*)(w1 + (long long)i*256 + jt*64 + q*4);
    }
    __syncthreads();
    {
      float aa[8][4];
      float b1v[4];
      #pragma unroll
      for (int c = 0; c < 4; ++c) b1v[c] = b1[jt*64 + ig*4 + c];
      #pragma unroll
      for (int r = 0; r < 8; ++r)
        #pragma unroll
        for (int c = 0; c < 4; ++c) aa[r][c] = b1v[c];
      #pragma unroll 4
      for (int i4 = 0; i4 < 32; ++i4) {
        float wc[4][4];
        #pragma unroll
        for (int d = 0; d < 4; ++d) {
          float4 u = *(const float4*)(wt + (i4*4 + d)*W1P + ig*4);
          wc[d][0] = u.x; wc[d][1] = u.y; wc[d][2] = u.z; wc[d][3] = u.w;
        }
        #pragma unroll
        for (int r = 0; r < 8; ++r) {
          float4 hv = *(const float4*)(hs + (tg + 16*r)*HSP + i4*4);
          #pragma unroll
          for (int c = 0; c < 4; ++c) {
            aa[r][c] = fmaf(hv.x, wc[0][c], aa[r][c]);
            aa[r][c] = fmaf(hv.y, wc[1][c], aa[r][c]);
            aa[r][c] = fmaf(hv.z, wc[2][c], aa[r][c]);
            aa[r][c] = fmaf(hv.w, wc[3][c], aa[r][c]);
          }
        }
      }
      #pragma unroll
      for (int r = 0; r < 8; ++r) {
        float4 o;
        o.x = fmaxf(aa[r][0], 0.0f); o.y = fmaxf(aa[r][1], 0.0f);
        o.z = fmaxf(aa[r][2], 0.0f); o.w = fmaxf(aa[r][3], 0.0f);
        *(float4*)(at + (tg + 16*r)*ATP + ig*4) = o;
      }
    }
    __syncthreads();
    for (int u = tid; u < 64*32; u += 256) {
      const int k = u >> 5, q = u & 31;
      *(float4*)(wt + k*W2P + q*4) =
          *(const float4*)(w2 + (long long)(jt*64 + k)*128 + q*4);
    }
    __syncthreads();
    #pragma unroll 2
    for (int k4 = 0; k4 < 16; ++k4) {
      float wr[4][8];
      #pragma unroll
      for (int d = 0; d < 4; ++d) {
        float4 u0 = *(const float4*)(wt + (k4*4 + d)*W2P + ig*8);
        float4 u1 = *(const float4*)(wt + (k4*4 + d)*W2P + ig*8 + 4);
        wr[d][0]=u0.x; wr[d][1]=u0.y; wr[d][2]=u0.z; wr[d][3]=u0.w;
        wr[d][4]=u1.x; wr[d][5]=u1.y; wr[d][6]=u1.z; wr[d][7]=u1.w;
      }
      #pragma unroll
      for (int r = 0; r < 8; ++r) {
        float4 av = *(const float4*)(at + (tg + 16*r)*ATP + k4*4);
        #pragma unroll
        for (int cc = 0; cc < 8; ++cc) {
          xacc[r][cc] = fmaf(av.x, wr[0][cc], xacc[r][cc]);
          xacc[r][cc] = fmaf(av.y, wr[1][cc], xacc[r][cc]);
          xacc[r][cc] = fmaf(av.z, wr[2][cc], xacc[r][cc]);
          xacc[r][cc] = fmaf(av.w, wr[3][cc], xacc[r][cc]);
        }
      }
    }
    __syncthreads();
  }

  {
    float b2v[8], gv[8], bv[8];
    #pragma unroll
    for (int cc = 0; cc < 8; ++cc) {
      b2v[cc] = b2[ig*8 + cc]; gv[cc] = lng[ig*8 + cc]; bv[cc] = lnb[ig*8 + cc];
    }
    #pragma unroll
    for (int r = 0; r < 8; ++r) {
      const int row = (tg + 16*r)*HSP + ig*8;
      float4 h0 = *(const float4*)(hs + row);
      float4 h1 = *(const float4*)(hs + row + 4);
      float xr[8];
      xr[0] = h0.x + (xacc[r][0] + b2v[0]);
      xr[1] = h0.y + (xacc[r][1] + b2v[1]);
      xr[2] = h0.z + (xacc[r][2] + b2v[2]);
      xr[3] = h0.w + (xacc[r][3] + b2v[3]);
      xr[4] = h1.x + (xacc[r][4] + b2v[4]);
      xr[5] = h1.y + (xacc[r][5] + b2v[5]);
      xr[6] = h1.z + (xacc[r][6] + b2v[6]);
      xr[7] = h1.w + (xacc[r][7] + b2v[7]);
      float s = xr[0]+xr[1]+xr[2]+xr[3]+xr[4]+xr[5]+xr[6]+xr[7];
      s += __shfl_xor(s, 1, 16); s += __shfl_xor(s, 2, 16);
      s += __shfl_xor(s, 4, 16); s += __shfl_xor(s, 8, 16);
      const float mu = s * 0.0078125f;
      float vs = 0.0f;
      #pragma unroll
      for (int cc = 0; cc < 8; ++cc) { float d = xr[cc]-mu; vs = fmaf(d, d, vs); }
      vs += __shfl_xor(vs, 1, 16); vs += __shfl_xor(vs, 2, 16);
      vs += __shfl_xor(vs, 4, 16); vs += __shfl_xor(vs, 8, 16);
      const float rstd = 1.0f / sqrtf(vs * 0.0078125f + C_LNEPS);
      float4 o0, o1;
      o0.x = (xr[0]-mu)*rstd*gv[0] + bv[0];
      o0.y = (xr[1]-mu)*rstd*gv[1] + bv[1];
      o0.z = (xr[2]-mu)*rstd*gv[2] + bv[2];
      o0.w = (xr[3]-mu)*rstd*gv[3] + bv[3];
      o1.x = (xr[4]-mu)*rstd*gv[4] + bv[4];
      o1.y = (xr[5]-mu)*rstd*gv[5] + bv[5];
      o1.z = (xr[6]-mu)*rstd*gv[6] + bv[6];
      o1.w = (xr[7]-mu)*rstd*gv[7] + bv[7];
      *(float4*)(hs + row) = o0;
      *(float4*)(hs + row + 4) = o1;
    }
  }
  __syncthreads();

  {
    float ky[8][8] = {};
    for (int kt = 0; kt < 2; ++kt) {
      for (int u = tid; u < 64*32; u += 256) {
        const int k = u >> 5, q = u & 31;
        *(float4*)(wt + k*W2P + q*4) =
            *(const float4*)(kp + (long long)(kt*64 + k)*128 + q*4);
      }
      __syncthreads();
      #pragma unroll 2
      for (int k4 = 0; k4 < 16; ++k4) {
        float wr[4][8];
        #pragma unroll
        for (int d = 0; d < 4; ++d) {
          float4 u0 = *(const float4*)(wt + (k4*4 + d)*W2P + ig*8);
          float4 u1 = *(const float4*)(wt + (k4*4 + d)*W2P + ig*8 + 4);
          wr[d][0]=u0.x; wr[d][1]=u0.y; wr[d][2]=u0.z; wr[d][3]=u0.w;
          wr[d][4]=u1.x; wr[d][5]=u1.y; wr[d][6]=u1.z; wr[d][7]=u1.w;
        }
        #pragma unroll
        for (int r = 0; r < 8; ++r) {
          float4 hv = *(const float4*)(hs + (tg + 16*r)*HSP + kt*64 + k4*4);
          #pragma unroll
          for (int cc = 0; cc < 8; ++cc) {
            ky[r][cc] = fmaf(hv.x, wr[0][cc], ky[r][cc]);
            ky[r][cc] = fmaf(hv.y, wr[1][cc], ky[r][cc]);
            ky[r][cc] = fmaf(hv.z, wr[2][cc], ky[r][cc]);
            ky[r][cc] = fmaf(hv.w, wr[3][cc], ky[r][cc]);
          }
        }
      }
      __syncthreads();
    }
    #pragma unroll
    for (int r = 0; r < 8; ++r) {
      const long long g = tokBase + tg + 16*r;
      float4 o0, o1;
      o0.x = ky[r][0]; o0.y = ky[r][1]; o0.z = ky[r][2]; o0.w = ky[r][3];
      o1.x = ky[r][4]; o1.y = ky[r][5]; o1.z = ky[r][6]; o1.w = ky[r][7];
      *(float4*)(keys + g*HD + ig*8) = o0;
      *(float4*)(keys + g*HD + ig*8 + 4) = o1;
    }
  }
}

// ---------------------------------------------------------------------------
// K3: the scan. 64 blocks x 512 threads (8 waves, 2/SIMD).
// Round-12: back to the spill-free 512-thread regime (rounds 2/4: VGPR
// 112-128, WRITE_SIZE exactly 4096 KB) while keeping the round-10 dataflow
// (kbuf triple-buffer, register-tiled U/fixup, LDS-only kf reuse). At 768
// threads the allocator pinned 84 VGPRs and ~7.5 MB/dispatch of scratch sat
// on the critical path (rounds 5-11, WRITE_SIZE 7.7-12 MB).
// Phase A (flat, all 512): staging loads kf(c+1)->regs early; U(c-1)
// 8ix4j reg tiles from kbuf[b3p]; fixup P(c) 2t'x4i reg tiles; staging
// stores last. Phase B: w0 recurrence (acc[16]x2 + bridge); w1-w4 P_pre
// 8t' shares; w5/w6/w7: G/Gx in 8 quarter-units (3/3/2) + norms on w7.
// SIMD map: S0={rec,P}, S1={P,3q}, S2={P,3q}, S3={P,2q+norms}.
// 2 barriers/chunk. Chunks < 29 provably dead (first fire t=931).
// Dynamic LDS = 163328 B.
// ---------------------------------------------------------------------------
#define C0 29
#define MSP 132   // Msh pitch
#define GPW 36    // G/Gx pitch
#define NT 512

#define INVB(buf,tok) Gxl[(tok)*GPW + 32 + (buf)]
#define TN2B(buf,tok) Gxl[(tok)*GPW + 34 + (buf)]

__device__ __forceinline__ float dpp_add_b1(float x){int y=__builtin_amdgcn_update_dpp(0,__float_as_int(x),0xB1,0xf,0xf,true);return x+__int_as_float(y);}
__device__ __forceinline__ float dpp_add_4e(float x){int y=__builtin_amdgcn_update_dpp(0,__float_as_int(x),0x4E,0xf,0xf,true);return x+__int_as_float(y);}
__device__ __forceinline__ float dpp_add_hm(float x){int y=__builtin_amdgcn_update_dpp(0,__float_as_int(x),0x141,0xf,0xf,true);return x+__int_as_float(y);}
__device__ __forceinline__ float dpp_add_mr(float x){int y=__builtin_amdgcn_update_dpp(0,__float_as_int(x),0x140,0xf,0xf,true);return x+__int_as_float(y);}
__device__ __forceinline__ float dpp_add_b15(float x){int y=__builtin_amdgcn_update_dpp(0,__float_as_int(x),0x142,0xf,0xf,true);return x+__int_as_float(y);}
__device__ __forceinline__ float dpp_add_b31(float x){int y=__builtin_amdgcn_update_dpp(0,__float_as_int(x),0x143,0xf,0xf,true);return x+__int_as_float(y);}

// G / Gx quarter-tile: 32 s-rows x 8 t-cols (cols [8q,8q+8)), one wave.
// Row pitch 128 with per-lane column rotation (2-way banks).
__device__ __forceinline__ void gram_q(const float* bufS, const float* bufT,
                                       float* dst, int q, int lane)
{
  const int sq = lane & 7, tq = lane >> 3;       // tq 0..7
  const int tcol = q*8 + tq;
  float ga[4] = {};
  for (int j4 = 0; j4 < 32; ++j4) {
    const int col = ((j4 + lane) & 31) * 4;
    const float4 tv = *(const float4*)(bufT + tcol*128 + col);
    #pragma unroll
    for (int r = 0; r < 4; ++r) {
      const float4 sv = *(const float4*)(bufS + (sq + 8*r)*128 + col);
      ga[r] = fmaf(sv.x, tv.x, ga[r]); ga[r] = fmaf(sv.y, tv.y, ga[r]);
      ga[r] = fmaf(sv.z, tv.z, ga[r]); ga[r] = fmaf(sv.w, tv.w, ga[r]);
    }
  }
  #pragma unroll
  for (int r = 0; r < 4; ++r)
    dst[(sq + 8*r)*GPW + tcol] = ga[r];
}

extern "C" __global__ __launch_bounds__(512)
void k_scan(const float* __restrict__ keys, float* __restrict__ Mg)
{
  extern __shared__ float sm[];
  float* Msh  = sm;                    // [128][132]           16896
  float* kbuf = Msh + 128*MSP;         // [3][32][128]         12288
  float* PW   = kbuf + 3*4096;         // [2][32][128]          8192
  float* Gb   = PW + 2*4096;           // [2][32][36]           2304
  float* Gxl  = Gb + 2*32*GPW;         // [32][36] (+inv/tn2)   1152
  // total 40832 floats = 163328 B

  const int tid  = threadIdx.x;
  const int lane = tid & 63;
  const int w    = tid >> 6;
  const int b    = blockIdx.x;
  const float* kb = keys + (long long)b * LD * HD;

  // ---------------- prologue ----------------
  for (int u = tid; u < 128*MSP; u += NT) Msh[u] = 0.0f;
  for (int u = tid; u < 4096; u += NT) PW[(C0&1)*4096 + u] = 0.0f;  // P(C0)=0
  {
    const int b30 = C0 % 3;   // = 2
    for (int u = tid; u < 1024; u += NT)
      *(float4*)(kbuf + b30*4096 + u*4) =
          *(const float4*)(kb + (long long)(C0*32)*HD + u*4);
  }
  __syncthreads();
  {
    const float* kc = kbuf + (C0%3)*4096;
    for (int u = tid; u < 1024; u += NT) {
      const int s = u >> 5, t = u & 31;
      float a = 0.0f;
      for (int j4 = 0; j4 < 32; ++j4) {
        const int col = ((j4 + tid) & 31) * 4;
        float4 sv = *(const float4*)(kc + s*128 + col);
        float4 tv = *(const float4*)(kc + t*128 + col);
        a = fmaf(sv.x,tv.x,a); a = fmaf(sv.y,tv.y,a);
        a = fmaf(sv.z,tv.z,a); a = fmaf(sv.w,tv.w,a);
      }
      Gb[(C0&1)*32*GPW + s*GPW + t] = a;
    }
  }
  if (tid < 256) {
    const int tok = tid >> 3, pp = tid & 7;
    const float* kc = kbuf + (C0%3)*4096;
    float ss = 0.0f;
    #pragma unroll
    for (int q = 0; q < 4; ++q) {
      float4 v = *(const float4*)(kc + tok*128 + pp*16 + q*4);
      ss = fmaf(v.x,v.x,ss); ss = fmaf(v.y,v.y,ss);
      ss = fmaf(v.z,v.z,ss); ss = fmaf(v.w,v.w,ss);
    }
    ss += __shfl_xor(ss,1,8); ss += __shfl_xor(ss,2,8); ss += __shfl_xor(ss,4,8);
    if (pp == 0) {
      const float n = sqrtf(ss);
      INVB(C0&1, tok) = 1.0f / fmaxf(n, C_NEPS);
      const float th = C_THMIN + C_THSPAN * (1.0f - (float)(C0*32 + tok) / 2047.0f);
      const float tn = th * n;
      TN2B(C0&1, tok) = tn * tn;
    }
  }
  __syncthreads();

  // ---------------- main loop ----------------
  for (int c = C0; c <= 64; ++c) {
    const int cur = c & 1, nxt = cur ^ 1;
    const int b3c = c % 3;            // kf(c)
    const int b3n = (c + 1) % 3;      // kf(c+1) dest
    const int b3p = (c + 2) % 3;      // == (c-1)%3, kf(c-1)
    const int t0 = c * 32;

    // ===== phase A (flat, all 512 threads) =====
    float4 kvl0, kvl1;
    if (c < 63) {   // staging loads issued early
      const float* src = kb + (long long)(t0 + 32)*HD;
      kvl0 = *(const float4*)(src + tid*4);
      kvl1 = *(const float4*)(src + (tid + 512)*4);
    }
    if (c > C0) {
      // U(c-1): M += alpha * W2_{c-1}^T kf_{c-1}   (8i x 4j register tiles)
      {
        const int it = tid >> 5;       // 0..15
        const int jt = tid & 31;       // 0..31
        const int i0 = it*8, j0 = jt*4;
        const float* Wp  = PW + nxt*4096;
        const float* kfp = kbuf + b3p*4096;
        float acc[8][4] = {};
        for (int s = 0; s < 32; ++s) {
          const float4 wa = *(const float4*)(Wp + s*128 + i0);
          const float4 wb = *(const float4*)(Wp + s*128 + i0 + 4);
          const float4 k4 = *(const float4*)(kfp + s*128 + j0);
          float wv[8] = {wa.x,wa.y,wa.z,wa.w,wb.x,wb.y,wb.z,wb.w};
          float kv[4] = {k4.x,k4.y,k4.z,k4.w};
          #pragma unroll
          for (int a = 0; a < 8; ++a)
            #pragma unroll
            for (int q = 0; q < 4; ++q)
              acc[a][q] = fmaf(wv[a], kv[q], acc[a][q]);
        }
        #pragma unroll
        for (int a = 0; a < 8; ++a) {
          float* mp = Msh + (i0 + a)*MSP + j0;
          float4 m = *(float4*)mp;
          m.x = fmaf(C_ALPHA, acc[a][0], m.x);
          m.y = fmaf(C_ALPHA, acc[a][1], m.y);
          m.z = fmaf(C_ALPHA, acc[a][2], m.z);
          m.w = fmaf(C_ALPHA, acc[a][3], m.w);
          *(float4*)mp = m;
        }
      }
      // fixup P(c) = Praw(c) + alpha * Gx(c-1,c)^T W2(c-1)  (2t' x 4i tiles)
      if (c <= 63) {
        const int tt2 = tid >> 5;            // 0..15 -> t' = tt2*2 + a
        const int i0f = (tid & 31) * 4;
        const float* Wp = PW + nxt*4096;
        float fac[2][4] = {};
        for (int s = 0; s < 32; ++s) {
          const float2 gx = *(const float2*)(Gxl + s*GPW + tt2*2);
          const float4 wp = *(const float4*)(Wp + s*128 + i0f);
          fac[0][0] = fmaf(gx.x, wp.x, fac[0][0]);
          fac[0][1] = fmaf(gx.x, wp.y, fac[0][1]);
          fac[0][2] = fmaf(gx.x, wp.z, fac[0][2]);
          fac[0][3] = fmaf(gx.x, wp.w, fac[0][3]);
          fac[1][0] = fmaf(gx.y, wp.x, fac[1][0]);
          fac[1][1] = fmaf(gx.y, wp.y, fac[1][1]);
          fac[1][2] = fmaf(gx.y, wp.z, fac[1][2]);
          fac[1][3] = fmaf(gx.y, wp.w, fac[1][3]);
        }
        float* Pp = PW + cur*4096;
        #pragma unroll
        for (int a = 0; a < 2; ++a) {
          float* pp = Pp + (tt2*2 + a)*128 + i0f;
          float4 p = *(float4*)pp;
          p.x = fmaf(C_ALPHA, fac[a][0], p.x);
          p.y = fmaf(C_ALPHA, fac[a][1], p.y);
          p.z = fmaf(C_ALPHA, fac[a][2], p.z);
          p.w = fmaf(C_ALPHA, fac[a][3], p.w);
          *(float4*)pp = p;
        }
      }
    }
    if (c < 63) {   // staging stores
      float* dst = kbuf + b3n*4096;
      *(float4*)(dst + tid*4) = kvl0;
      *(float4*)(dst + (tid + 512)*4) = kvl1;
    }
    __syncthreads();
    if (c == 64) break;

    // ===== phase B (role waves) =====
    if (w == 0) {
      // in-wave recurrence, acc[16] x 2 halves + register bridge
      float* Pc = PW + cur*4096;
      const float* kfc = kbuf + b3c*4096;
      const float* Gc  = Gb + cur*32*GPW;
      const int l2 = lane*2;
      float2 acc[16];
      #pragma unroll
      for (int u = 0; u < 16; ++u) { acc[u].x = 0.0f; acc[u].y = 0.0f; }
      // ---- half 0: t = 0..15
      #pragma unroll
      for (int t = 0; t < 16; ++t) {
        const float2 p2 = *(const float2*)(Pc + t*128 + l2);
        const float2 k2 = *(const float2*)(kfc + t*128 + l2);
        const float it = INVB(cur, t);
        const float vx = it * fmaf(C_ALPHA, acc[t].x, p2.x);
        const float vy = it * fmaf(C_ALPHA, acc[t].y, p2.y);
        const float ex = k2.x - vx;
        const float ey = k2.y - vy;
        float e2 = fmaf(ex, ex, ey*ey);
        e2 = dpp_add_b1(e2); e2 = dpp_add_4e(e2);
        e2 = dpp_add_hm(e2); e2 = dpp_add_mr(e2);
        e2 = dpp_add_b15(e2); e2 = dpp_add_b31(e2);
        const float en2 = __int_as_float(__builtin_amdgcn_readlane(__float_as_int(e2), 63));
        const bool fire = (en2 >= TN2B(cur, t));
        const float wx = fire ? ex * it : 0.0f;
        const float wy = fire ? ey * it : 0.0f;
        float2 w2v; w2v.x = wx; w2v.y = wy;
        *(float2*)(Pc + t*128 + l2) = w2v;
        const float* gr = Gc + t*GPW;
        #pragma unroll
        for (int u4 = (t+1) & ~3; u4 < 16; u4 += 4) {
          const float4 g = *(const float4*)(gr + u4);
          acc[u4+0].x = fmaf(wx, g.x, acc[u4+0].x); acc[u4+0].y = fmaf(wy, g.x, acc[u4+0].y);
          acc[u4+1].x = fmaf(wx, g.y, acc[u4+1].x); acc[u4+1].y = fmaf(wy, g.y, acc[u4+1].y);
          acc[u4+2].x = fmaf(wx, g.z, acc[u4+2].x); acc[u4+2].y = fmaf(wy, g.z, acc[u4+2].y);
          acc[u4+3].x = fmaf(wx, g.w, acc[u4+3].x); acc[u4+3].y = fmaf(wy, g.w, acc[u4+3].y);
        }
      }
      // ---- bridge: acc[u] = sum_{s<16} w2[s] * G[s][16+u]  (G symmetric)
      #pragma unroll
      for (int u = 0; u < 16; ++u) { acc[u].x = 0.0f; acc[u].y = 0.0f; }
      #pragma unroll
      for (int s = 0; s < 16; ++s) {
        const float2 ws = *(const float2*)(Pc + s*128 + l2);
        const float* gs = Gc + s*GPW + 16;
        #pragma unroll
        for (int u4 = 0; u4 < 16; u4 += 4) {
          const float4 g = *(const float4*)(gs + u4);
          acc[u4+0].x = fmaf(ws.x, g.x, acc[u4+0].x); acc[u4+0].y = fmaf(ws.y, g.x, acc[u4+0].y);
          acc[u4+1].x = fmaf(ws.x, g.y, acc[u4+1].x); acc[u4+1].y = fmaf(ws.y, g.y, acc[u4+1].y);
          acc[u4+2].x = fmaf(ws.x, g.z, acc[u4+2].x); acc[u4+2].y = fmaf(ws.y, g.z, acc[u4+2].y);
          acc[u4+3].x = fmaf(ws.x, g.w, acc[u4+3].x); acc[u4+3].y = fmaf(ws.y, g.w, acc[u4+3].y);
        }
      }
      // ---- half 1: t = 16..31
      #pragma unroll
      for (int t = 16; t < 32; ++t) {
        const int tt = t - 16;
        const float2 p2 = *(const float2*)(Pc + t*128 + l2);
        const float2 k2 = *(const float2*)(kfc + t*128 + l2);
        const float it = INVB(cur, t);
        const float vx = it * fmaf(C_ALPHA, acc[tt].x, p2.x);
        const float vy = it * fmaf(C_ALPHA, acc[tt].y, p2.y);
        const float ex = k2.x - vx;
        const float ey = k2.y - vy;
        float e2 = fmaf(ex, ex, ey*ey);
        e2 = dpp_add_b1(e2); e2 = dpp_add_4e(e2);
        e2 = dpp_add_hm(e2); e2 = dpp_add_mr(e2);
        e2 = dpp_add_b15(e2); e2 = dpp_add_b31(e2);
        const float en2 = __int_as_float(__builtin_amdgcn_readlane(__float_as_int(e2), 63));
        const bool fire = (en2 >= TN2B(cur, t)) && (t0 + t < NSTEP);
        const float wx = fire ? ex * it : 0.0f;
        const float wy = fire ? ey * it : 0.0f;
        float2 w2v; w2v.x = wx; w2v.y = wy;
        *(float2*)(Pc + t*128 + l2) = w2v;
        const float* gr = Gc + t*GPW + 16;
        #pragma unroll
        for (int u4 = (tt+1) & ~3; u4 < 16; u4 += 4) {
          const float4 g = *(const float4*)(gr + u4);
          acc[u4+0].x = fmaf(wx, g.x, acc[u4+0].x); acc[u4+0].y = fmaf(wy, g.x, acc[u4+0].y);
          acc[u4+1].x = fmaf(wx, g.y, acc[u4+1].x); acc[u4+1].y = fmaf(wy, g.y, acc[u4+1].y);
          acc[u4+2].x = fmaf(wx, g.z, acc[u4+2].x); acc[u4+2].y = fmaf(wy, g.z, acc[u4+2].y);
          acc[u4+3].x = fmaf(wx, g.w, acc[u4+3].x); acc[u4+3].y = fmaf(wy, g.w, acc[u4+3].y);
        }
      }
    } else if (c < 63) {
      if (w <= 4) {
        // P_pre(c+1) share: t' in [8(w-1), 8(w-1)+8), all 128 i
        const float* kfn = kbuf + b3n*4096;
        const int tb8 = (w - 1) * 8;
        const int ib = lane & 31, ih = lane >> 5;
        float pa[8][2] = {};
        for (int j4 = 0; j4 < 32; ++j4) {
          float4 mv[2];
          #pragma unroll
          for (int r = 0; r < 2; ++r)
            mv[r] = *(const float4*)(Msh + (ib + 32*(ih + 2*r))*MSP + j4*4);
          #pragma unroll
          for (int ss = 0; ss < 8; ++ss) {
            const float4 kv = *(const float4*)(kfn + (tb8+ss)*128 + j4*4);
            pa[ss][0] = fmaf(kv.x, mv[0].x, pa[ss][0]);
            pa[ss][0] = fmaf(kv.y, mv[0].y, pa[ss][0]);
            pa[ss][0] = fmaf(kv.z, mv[0].z, pa[ss][0]);
            pa[ss][0] = fmaf(kv.w, mv[0].w, pa[ss][0]);
            pa[ss][1] = fmaf(kv.x, mv[1].x, pa[ss][1]);
            pa[ss][1] = fmaf(kv.y, mv[1].y, pa[ss][1]);
            pa[ss][1] = fmaf(kv.z, mv[1].z, pa[ss][1]);
            pa[ss][1] = fmaf(kv.w, mv[1].w, pa[ss][1]);
          }
        }
        float* Pp = PW + nxt*4096;
        #pragma unroll
        for (int ss = 0; ss < 8; ++ss)
          #pragma unroll
          for (int r = 0; r < 2; ++r)
            Pp[(tb8+ss)*128 + ib + 32*(ih + 2*r)] = pa[ss][r];
      } else if (w == 5) {
        // G quarters 0,1,2
        gram_q(kbuf + b3n*4096, kbuf + b3n*4096, Gb + nxt*32*GPW, 0, lane);
        gram_q(kbuf + b3n*4096, kbuf + b3n*4096, Gb + nxt*32*GPW, 1, lane);
        gram_q(kbuf + b3n*4096, kbuf + b3n*4096, Gb + nxt*32*GPW, 2, lane);
      } else if (w == 6) {
        // G quarter 3, Gx quarters 0,1
        gram_q(kbuf + b3n*4096, kbuf + b3n*4096, Gb + nxt*32*GPW, 3, lane);
        gram_q(kbuf + b3c*4096, kbuf + b3n*4096, Gxl, 0, lane);
        gram_q(kbuf + b3c*4096, kbuf + b3n*4096, Gxl, 1, lane);
      } else {
        // w == 7: Gx quarters 2,3 + norms(c+1)
        gram_q(kbuf + b3c*4096, kbuf + b3n*4096, Gxl, 2, lane);
        gram_q(kbuf + b3c*4096, kbuf + b3n*4096, Gxl, 3, lane);
        const float* kn = kbuf + b3n*4096;
        const int tok = lane >> 1, hh = lane & 1;
        float ss2 = 0.0f;
        #pragma unroll
        for (int q = 0; q < 16; ++q) {
          const int cq = (q + lane) & 15;
          float4 v = *(const float4*)(kn + tok*128 + hh*64 + cq*4);
          ss2 = fmaf(v.x,v.x,ss2); ss2 = fmaf(v.y,v.y,ss2);
          ss2 = fmaf(v.z,v.z,ss2); ss2 = fmaf(v.w,v.w,ss2);
        }
        ss2 += __shfl_xor(ss2, 1);
        if (hh == 0) {
          const float n = sqrtf(ss2);
          INVB(nxt, tok) = 1.0f / fmaxf(n, C_NEPS);
          const float th = C_THMIN + C_THSPAN * (1.0f - (float)(t0 + 32 + tok) / 2047.0f);
          const float tn = th * n;
          TN2B(nxt, tok) = tn * tn;
        }
      }
    }
    __syncthreads();
  }

  // store M
  for (int u = tid; u < 4096; u += NT) {
    const int i = u >> 5, q = u & 31;
    *(float4*)(Mg + (long long)b*16384 + i*128 + q*4) =
        *(const float4*)(Msh + i*MSP + q*4);
  }
}

// ---------------------------------------------------------------------------
// K4a: read = M @ q ; rr = read @ rp_w + rp_b     (64 blocks x 128 threads)
// ---------------------------------------------------------------------------
extern "C" __global__ __launch_bounds__(128, 1)
void k_read(const float* __restrict__ keys, const float* __restrict__ Mg,
            const float* __restrict__ rpw, const float* __restrict__ rpb,
            float* __restrict__ rr)
{
  __shared__ float qv[128];
  __shared__ float rd[128];
  const int b = blockIdx.x, tid = threadIdx.x;
  qv[tid] = keys[((long long)b*LD + (LD-1))*HD + tid];
  __syncthreads();
  float acc = 0.0f;
  const float* Mrow = Mg + (long long)b*16384 + (long long)tid*128;
  for (int j4 = 0; j4 < 32; ++j4) {
    float4 m = *(const float4*)(Mrow + j4*4);
    acc = fmaf(m.x, qv[j4*4+0], acc);
    acc = fmaf(m.y, qv[j4*4+1], acc);
    acc = fmaf(m.z, qv[j4*4+2], acc);
    acc = fmaf(m.w, qv[j4*4+3], acc);
  }
  rd[tid] = acc;
  __syncthreads();
  float a2 = rpb[tid];
  for (int k = 0; k < 128; ++k) a2 = fmaf(rd[k], rpw[k*128 + tid], a2);
  rr[b*128 + tid] = a2;
}

// ---------------------------------------------------------------------------
// K4b: out[b][v] = rr[b] . out_w[:,v] + out_b[v]   (250 blocks x 256 threads)
// ---------------------------------------------------------------------------
extern "C" __global__ __launch_bounds__(256, 1)
void k_out(const float* __restrict__ rr, const float* __restrict__ outw,
           const float* __restrict__ outb, float* __restrict__ out)
{
  __shared__ float rl[64*128];
  const int tid = threadIdx.x;
  for (int u = tid; u < 8192; u += 256) rl[u] = rr[u];
  __syncthreads();
  const int v = blockIdx.x*128 + (tid & 127);
  const int bg = tid >> 7;
  const float ob = outb[v];
  float acc[32];
  #pragma unroll
  for (int bb = 0; bb < 32; ++bb) acc[bb] = 0.0f;
  for (int h = 0; h < 128; ++h) {
    const float wv = outw[(long long)h*VD + v];
    #pragma unroll
    for (int bb = 0; bb < 32; ++bb)
      acc[bb] = fmaf(rl[(bg*32 + bb)*128 + h], wv, acc[bb]);
  }
  #pragma unroll
  for (int bb = 0; bb < 32; ++bb)
    out[(long long)(bg*32 + bb)*VD + v] = acc[bb] + ob;
}

// ---------------------------------------------------------------------------
extern "C" void kernel_launch(void* const* d_in, const int* in_sizes, int n_in,
                              void* d_out, int out_size, void* d_ws, size_t ws_size,
                              hipStream_t stream)
{
  const int*   seq   = (const int*)d_in[0];
  const float* embed = (const float*)d_in[1];
  const float* w1    = (const float*)d_in[2];
  const float* b1    = (const float*)d_in[3];
  const float* w2    = (const float*)d_in[4];
  const float* b2    = (const float*)d_in[5];
  const float* ln_g  = (const float*)d_in[6];
  const float* ln_b  = (const float*)d_in[7];
  const float* kp_w  = (const float*)d_in[8];
  const float* rp_w  = (const float*)d_in[9];
  const float* rp_b  = (const float*)d_in[10];
  const float* out_w = (const float*)d_in[11];
  const float* out_b = (const float*)d_in[12];
  float* out = (float*)d_out;

  char* ws = (char*)d_ws;
  float* keys = (float*)ws;                               // 64 MiB
  float* Mg   = (float*)(ws + 67108864);                  // 4 MiB
  float* rr   = (float*)(ws + 67108864 + 4194304);        // 32 KiB

  hipLaunchKernelGGL(k_tokens, dim3(64*TBLK), dim3(256), 137216, stream,
                     seq, embed, w1, b1, w2, b2, ln_g, ln_b, kp_w, keys);
  hipLaunchKernelGGL(k_scan, dim3(64), dim3(512), 163328, stream, keys, Mg);
  hipLaunchKernelGGL(k_read, dim3(64), dim3(128), 0, stream, keys, Mg, rp_w, rp_b, rr);
  hipLaunchKernelGGL(k_out, dim3(250), dim3(256), 0, stream, rr, out_w, out_b, out);
}

// Round 13
// 776.992 us; speedup vs baseline: 1.2480x; 1.2480x over previous
//
#include <hip/hip_runtime.h>

#define HD 128
#define LD 2048
#define BD 64
#define VD 32000
#define NSTEP 2047   // L-1 scan steps, t = 0..2046

// f32 constants exactly matching the reference's f32-cast scalars
#define C_ALPHA  0.05f
#define C_THMIN  0.4f
#define C_THSPAN 1.1f
#define C_NEPS   1e-12f
#define C_LNEPS  1e-5f

// ---------------------------------------------------------------------------
// K1: fused embed-gather + MLP + LayerNorm + keys=hn@kp.
// Round-13: 512 threads (was 256). 137KB LDS caps at 1 block/CU, so 256
// threads meant 1 wave/SIMD = zero latency hiding; 512 gives 2/SIMD.
// Same LDS layout and the SAME per-element accumulation order (i4/d, k4/d)
// so keys are bit-identical; only the LN shuffle-reduce tree changes
// (16-lane x8 -> 32-lane x4 partials, ~1e-7 reassociation).
// Only tokens >= 896 are live (first possible fire is t=931).
// ---------------------------------------------------------------------------
#define HSP 132
#define W1P 68
#define W2P 132
#define ATP 68
#define TOK0 896
#define TBLK 9

extern "C" __global__ __launch_bounds__(512, 1)
void k_tokens(const int* __restrict__ seq, const float* __restrict__ embed,
              const float* __restrict__ w1, const float* __restrict__ b1,
              const float* __restrict__ w2, const float* __restrict__ b2,
              const float* __restrict__ lng, const float* __restrict__ lnb,
              const float* __restrict__ kp, float* __restrict__ keys)
{
  extern __shared__ float sm[];
  float* hs = sm;                 // [128][HSP]  h, later hn
  float* wt = sm + 128*HSP;       // [128][W1P] (w1 tile) or [64][W2P] (w2/kp)
  float* at = wt + 128*W1P;       // [128][ATP]  relu tile
  const int tid = threadIdx.x;
  const int bb  = blockIdx.x / TBLK;
  const int rel = blockIdx.x % TBLK;
  const long long tokBase = (long long)bb * LD + TOK0 + rel * 128;

  // ---- gather h = embed[seq]
  for (int u = tid; u < 128*32; u += 512) {
    const int tok = u >> 5, seg = u & 31;
    const int s = seq[tokBase + tok];
    *(float4*)(hs + tok*HSP + seg*4) =
        *(const float4*)(embed + (long long)s*HD + seg*4);
  }
  __syncthreads();

  const int tg = tid >> 5;   // token group 0..15: tok = tg + 16*r, r=0..7
  const int ig = tid & 31;   // column group 0..31

  float xacc[8][4] = {};     // x (MLP out): 8 tok x 4 i (i = ig*4+q)

  for (int jt = 0; jt < 4; ++jt) {
    // stage w1 tile [128 i][64 j]
    for (int u = tid; u < 128*16; u += 512) {
      const int i = u >> 4, q = u & 15;
      *(float4*)(wt + i*W1P + q*4) =
          *(const float4*)(w1 + (long long)i*256 + jt*64 + q*4);
    }
    __syncthreads();
    // a-tile = relu(h @ w1tile + b1): thread = 8 tok x 2 j  (j = ig*2+c)
    {
      float aa[8][2];
      float b1v[2];
      b1v[0] = b1[jt*64 + ig*2];
      b1v[1] = b1[jt*64 + ig*2 + 1];
      #pragma unroll
      for (int r = 0; r < 8; ++r) { aa[r][0] = b1v[0]; aa[r][1] = b1v[1]; }
      #pragma unroll 4
      for (int i4 = 0; i4 < 32; ++i4) {
        float2 wc[4];
        #pragma unroll
        for (int d = 0; d < 4; ++d)
          wc[d] = *(const float2*)(wt + (i4*4 + d)*W1P + ig*2);
        #pragma unroll
        for (int r = 0; r < 8; ++r) {
          float4 hv = *(const float4*)(hs + (tg + 16*r)*HSP + i4*4);
          aa[r][0] = fmaf(hv.x, wc[0].x, aa[r][0]);
          aa[r][0] = fmaf(hv.y, wc[1].x, aa[r][0]);
          aa[r][0] = fmaf(hv.z, wc[2].x, aa[r][0]);
          aa[r][0] = fmaf(hv.w, wc[3].x, aa[r][0]);
          aa[r][1] = fmaf(hv.x, wc[0].y, aa[r][1]);
          aa[r][1] = fmaf(hv.y, wc[1].y, aa[r][1]);
          aa[r][1] = fmaf(hv.z, wc[2].y, aa[r][1]);
          aa[r][1] = fmaf(hv.w, wc[3].y, aa[r][1]);
        }
      }
      #pragma unroll
      for (int r = 0; r < 8; ++r) {
        float2 o;
        o.x = fmaxf(aa[r][0], 0.0f);
        o.y = fmaxf(aa[r][1], 0.0f);
        *(float2*)(at + (tg + 16*r)*ATP + ig*2) = o;
      }
    }
    __syncthreads();
    // stage w2 tile [64 k][128 i]
    for (int u = tid; u < 64*32; u += 512) {
      const int k = u >> 5, q = u & 31;
      *(float4*)(wt + k*W2P + q*4) =
          *(const float4*)(w2 + (long long)(jt*64 + k)*128 + q*4);
    }
    __syncthreads();
    // x += a-tile @ w2tile: thread = 8 tok x 4 i
    #pragma unroll 2
    for (int k4 = 0; k4 < 16; ++k4) {
      float4 wr[4];
      #pragma unroll
      for (int d = 0; d < 4; ++d)
        wr[d] = *(const float4*)(wt + (k4*4 + d)*W2P + ig*4);
      #pragma unroll
      for (int r = 0; r < 8; ++r) {
        float4 av = *(const float4*)(at + (tg + 16*r)*ATP + k4*4);
        xacc[r][0] = fmaf(av.x, wr[0].x, xacc[r][0]);
        xacc[r][0] = fmaf(av.y, wr[1].x, xacc[r][0]);
        xacc[r][0] = fmaf(av.z, wr[2].x, xacc[r][0]);
        xacc[r][0] = fmaf(av.w, wr[3].x, xacc[r][0]);
        xacc[r][1] = fmaf(av.x, wr[0].y, xacc[r][1]);
        xacc[r][1] = fmaf(av.y, wr[1].y, xacc[r][1]);
        xacc[r][1] = fmaf(av.z, wr[2].y, xacc[r][1]);
        xacc[r][1] = fmaf(av.w, wr[3].y, xacc[r][1]);
        xacc[r][2] = fmaf(av.x, wr[0].z, xacc[r][2]);
        xacc[r][2] = fmaf(av.y, wr[1].z, xacc[r][2]);
        xacc[r][2] = fmaf(av.z, wr[2].z, xacc[r][2]);
        xacc[r][2] = fmaf(av.w, wr[3].z, xacc[r][2]);
        xacc[r][3] = fmaf(av.x, wr[0].w, xacc[r][3]);
        xacc[r][3] = fmaf(av.y, wr[1].w, xacc[r][3]);
        xacc[r][3] = fmaf(av.z, wr[2].w, xacc[r][3]);
        xacc[r][3] = fmaf(av.w, wr[3].w, xacc[r][3]);
      }
    }
    __syncthreads();
  }

  // ---- x = h + (x + b2); LayerNorm (32 lanes share a token); hn -> hs
  {
    float b2v[4], gv[4], bv[4];
    #pragma unroll
    for (int q = 0; q < 4; ++q) {
      b2v[q] = b2[ig*4 + q]; gv[q] = lng[ig*4 + q]; bv[q] = lnb[ig*4 + q];
    }
    #pragma unroll
    for (int r = 0; r < 8; ++r) {
      const int row = (tg + 16*r)*HSP + ig*4;
      float4 h0 = *(const float4*)(hs + row);
      float xr[4];
      xr[0] = h0.x + (xacc[r][0] + b2v[0]);
      xr[1] = h0.y + (xacc[r][1] + b2v[1]);
      xr[2] = h0.z + (xacc[r][2] + b2v[2]);
      xr[3] = h0.w + (xacc[r][3] + b2v[3]);
      float s = xr[0] + xr[1] + xr[2] + xr[3];
      s += __shfl_xor(s, 1, 32);  s += __shfl_xor(s, 2, 32);
      s += __shfl_xor(s, 4, 32);  s += __shfl_xor(s, 8, 32);
      s += __shfl_xor(s, 16, 32);
      const float mu = s * 0.0078125f;
      float vs = 0.0f;
      #pragma unroll
      for (int q = 0; q < 4; ++q) { float d = xr[q]-mu; vs = fmaf(d, d, vs); }
      vs += __shfl_xor(vs, 1, 32);  vs += __shfl_xor(vs, 2, 32);
      vs += __shfl_xor(vs, 4, 32);  vs += __shfl_xor(vs, 8, 32);
      vs += __shfl_xor(vs, 16, 32);
      const float rstd = 1.0f / sqrtf(vs * 0.0078125f + C_LNEPS);
      float4 o;
      o.x = (xr[0]-mu)*rstd*gv[0] + bv[0];
      o.y = (xr[1]-mu)*rstd*gv[1] + bv[1];
      o.z = (xr[2]-mu)*rstd*gv[2] + bv[2];
      o.w = (xr[3]-mu)*rstd*gv[3] + bv[3];
      *(float4*)(hs + row) = o;
    }
  }
  __syncthreads();

  // ---- keys = hn @ kp
  {
    float ky[8][4] = {};
    for (int kt = 0; kt < 2; ++kt) {
      for (int u = tid; u < 64*32; u += 512) {
        const int k = u >> 5, q = u & 31;
        *(float4*)(wt + k*W2P + q*4) =
            *(const float4*)(kp + (long long)(kt*64 + k)*128 + q*4);
      }
      __syncthreads();
      #pragma unroll 2
      for (int k4 = 0; k4 < 16; ++k4) {
        float4 wr[4];
        #pragma unroll
        for (int d = 0; d < 4; ++d)
          wr[d] = *(const float4*)(wt + (k4*4 + d)*W2P + ig*4);
        #pragma unroll
        for (int r = 0; r < 8; ++r) {
          float4 hv = *(const float4*)(hs + (tg + 16*r)*HSP + kt*64 + k4*4);
          ky[r][0] = fmaf(hv.x, wr[0].x, ky[r][0]);
          ky[r][0] = fmaf(hv.y, wr[1].x, ky[r][0]);
          ky[r][0] = fmaf(hv.z, wr[2].x, ky[r][0]);
          ky[r][0] = fmaf(hv.w, wr[3].x, ky[r][0]);
          ky[r][1] = fmaf(hv.x, wr[0].y, ky[r][1]);
          ky[r][1] = fmaf(hv.y, wr[1].y, ky[r][1]);
          ky[r][1] = fmaf(hv.z, wr[2].y, ky[r][1]);
          ky[r][1] = fmaf(hv.w, wr[3].y, ky[r][1]);
          ky[r][2] = fmaf(hv.x, wr[0].z, ky[r][2]);
          ky[r][2] = fmaf(hv.y, wr[1].z, ky[r][2]);
          ky[r][2] = fmaf(hv.z, wr[2].z, ky[r][2]);
          ky[r][2] = fmaf(hv.w, wr[3].z, ky[r][2]);
          ky[r][3] = fmaf(hv.x, wr[0].w, ky[r][3]);
          ky[r][3] = fmaf(hv.y, wr[1].w, ky[r][3]);
          ky[r][3] = fmaf(hv.z, wr[2].w, ky[r][3]);
          ky[r][3] = fmaf(hv.w, wr[3].w, ky[r][3]);
        }
      }
      __syncthreads();
    }
    #pragma unroll
    for (int r = 0; r < 8; ++r) {
      const long long g = tokBase + tg + 16*r;
      float4 o;
      o.x = ky[r][0]; o.y = ky[r][1]; o.z = ky[r][2]; o.w = ky[r][3];
      *(float4*)(keys + g*HD + ig*4) = o;
    }
  }
}

// ---------------------------------------------------------------------------
// K3: the scan — ROUND-11 exact (best measured: 462 us). 64 blocks x 768
// threads (12 waves, 3/SIMD). Round-12's 512-thread variant regressed
// (652 us): 2 waves/SIMD lost the TLP that was hiding LDS/serial latency,
// and the spill persisted anyway. Keeping 768 + known role balance.
// Phase A: U (waves 0-7, 8ix4j reg tiles, kf(c-1) from LDS triple-buffer);
// fixup+staging (waves 8-11). Phase B: S0 = recurrence(w0) + 2 P_pre(w4,w8)
// (+norms on w4); S1(w1,w5,w9) + S2(w2,w6,w10) = 6 P_pre; S3: w3=G h0,
// w7=G h1, w11=Gx h0+h1. 2 barriers/chunk. Chunks < 29 provably dead.
// Dynamic LDS = 163328 B.
// ---------------------------------------------------------------------------
#define C0 29
#define MSP 132   // Msh pitch
#define GPW 36    // G/Gx pitch
#define NT 768

#define INVB(buf,tok) Gxl[(tok)*GPW + 32 + (buf)]
#define TN2B(buf,tok) Gxl[(tok)*GPW + 34 + (buf)]

__device__ __forceinline__ float dpp_add_b1(float x){int y=__builtin_amdgcn_update_dpp(0,__float_as_int(x),0xB1,0xf,0xf,true);return x+__int_as_float(y);}
__device__ __forceinline__ float dpp_add_4e(float x){int y=__builtin_amdgcn_update_dpp(0,__float_as_int(x),0x4E,0xf,0xf,true);return x+__int_as_float(y);}
__device__ __forceinline__ float dpp_add_hm(float x){int y=__builtin_amdgcn_update_dpp(0,__float_as_int(x),0x141,0xf,0xf,true);return x+__int_as_float(y);}
__device__ __forceinline__ float dpp_add_mr(float x){int y=__builtin_amdgcn_update_dpp(0,__float_as_int(x),0x140,0xf,0xf,true);return x+__int_as_float(y);}
__device__ __forceinline__ float dpp_add_b15(float x){int y=__builtin_amdgcn_update_dpp(0,__float_as_int(x),0x142,0xf,0xf,true);return x+__int_as_float(y);}
__device__ __forceinline__ float dpp_add_b31(float x){int y=__builtin_amdgcn_update_dpp(0,__float_as_int(x),0x143,0xf,0xf,true);return x+__int_as_float(y);}

// G / Gx half-tile: 32 s-rows x 16 t-cols, one wave. Row pitch 128 with
// per-lane column rotation (2-way banks). Stride-8 row blocking.
__device__ __forceinline__ void gram_half(const float* bufS, const float* bufT,
                                          float* dst, int half, int lane)
{
  const int sq = lane & 7, tq = lane >> 3;
  float ga[4][2] = {};
  for (int j4 = 0; j4 < 32; ++j4) {
    const int col = ((j4 + lane) & 31) * 4;
    float4 sv[4], tv[2];
    #pragma unroll
    for (int r = 0; r < 4; ++r)
      sv[r] = *(const float4*)(bufS + (sq + 8*r)*128 + col);
    #pragma unroll
    for (int q = 0; q < 2; ++q)
      tv[q] = *(const float4*)(bufT + (half*16 + tq*2 + q)*128 + col);
    #pragma unroll
    for (int r = 0; r < 4; ++r)
      #pragma unroll
      for (int q = 0; q < 2; ++q) {
        ga[r][q] = fmaf(sv[r].x, tv[q].x, ga[r][q]);
        ga[r][q] = fmaf(sv[r].y, tv[q].y, ga[r][q]);
        ga[r][q] = fmaf(sv[r].z, tv[q].z, ga[r][q]);
        ga[r][q] = fmaf(sv[r].w, tv[q].w, ga[r][q]);
      }
  }
  #pragma unroll
  for (int r = 0; r < 4; ++r)
    #pragma unroll
    for (int q = 0; q < 2; ++q)
      dst[(sq + 8*r)*GPW + half*16 + tq*2 + q] = ga[r][q];
}

extern "C" __global__ __launch_bounds__(768)
void k_scan(const float* __restrict__ keys, float* __restrict__ Mg)
{
  extern __shared__ float sm[];
  float* Msh  = sm;                    // [128][132]           16896
  float* kbuf = Msh + 128*MSP;         // [3][32][128]         12288
  float* PW   = kbuf + 3*4096;         // [2][32][128]          8192
  float* Gb   = PW + 2*4096;           // [2][32][36]           2304
  float* Gxl  = Gb + 2*32*GPW;         // [32][36] (+inv/tn2)   1152
  // total 40832 floats = 163328 B

  const int tid  = threadIdx.x;
  const int lane = tid & 63;
  const int w    = tid >> 6;
  const int b    = blockIdx.x;
  const float* kb = keys + (long long)b * LD * HD;

  // ---------------- prologue ----------------
  for (int u = tid; u < 128*MSP; u += NT) Msh[u] = 0.0f;
  for (int u = tid; u < 4096; u += NT) PW[(C0&1)*4096 + u] = 0.0f;  // P(C0)=0
  {
    const int b30 = C0 % 3;   // = 2
    for (int u = tid; u < 1024; u += NT)
      *(float4*)(kbuf + b30*4096 + u*4) =
          *(const float4*)(kb + (long long)(C0*32)*HD + u*4);
  }
  __syncthreads();
  {
    const float* kc = kbuf + (C0%3)*4096;
    for (int u = tid; u < 1024; u += NT) {
      const int s = u >> 5, t = u & 31;
      float a = 0.0f;
      for (int j4 = 0; j4 < 32; ++j4) {
        const int col = ((j4 + tid) & 31) * 4;
        float4 sv = *(const float4*)(kc + s*128 + col);
        float4 tv = *(const float4*)(kc + t*128 + col);
        a = fmaf(sv.x,tv.x,a); a = fmaf(sv.y,tv.y,a);
        a = fmaf(sv.z,tv.z,a); a = fmaf(sv.w,tv.w,a);
      }
      Gb[(C0&1)*32*GPW + s*GPW + t] = a;
    }
  }
  if (tid < 256) {
    const int tok = tid >> 3, pp = tid & 7;
    const float* kc = kbuf + (C0%3)*4096;
    float ss = 0.0f;
    #pragma unroll
    for (int q = 0; q < 4; ++q) {
      float4 v = *(const float4*)(kc + tok*128 + pp*16 + q*4);
      ss = fmaf(v.x,v.x,ss); ss = fmaf(v.y,v.y,ss);
      ss = fmaf(v.z,v.z,ss); ss = fmaf(v.w,v.w,ss);
    }
    ss += __shfl_xor(ss,1,8); ss += __shfl_xor(ss,2,8); ss += __shfl_xor(ss,4,8);
    if (pp == 0) {
      const float n = sqrtf(ss);
      INVB(C0&1, tok) = 1.0f / fmaxf(n, C_NEPS);
      const float th = C_THMIN + C_THSPAN * (1.0f - (float)(C0*32 + tok) / 2047.0f);
      const float tn = th * n;
      TN2B(C0&1, tok) = tn * tn;
    }
  }
  __syncthreads();

  // ---------------- main loop ----------------
  for (int c = C0; c <= 64; ++c) {
    const int cur = c & 1, nxt = cur ^ 1;
    const int b3c = c % 3;            // kf(c)
    const int b3n = (c + 1) % 3;      // kf(c+1) dest
    const int b3p = (c + 2) % 3;      // == (c-1)%3, kf(c-1)
    const int t0 = c * 32;

    // ===== phase A =====
    if (w < 8) {
      // U(c-1): M += alpha * W2_{c-1}^T kf_{c-1}   (8i x 4j register tiles)
      if (c > C0) {
        const int it = tid >> 5;       // 0..15
        const int jt = tid & 31;       // 0..31
        const int i0 = it*8, j0 = jt*4;
        const float* Wp  = PW + nxt*4096;
        const float* kfp = kbuf + b3p*4096;
        float acc[8][4] = {};
        for (int s = 0; s < 32; ++s) {
          const float4 wa = *(const float4*)(Wp + s*128 + i0);
          const float4 wb = *(const float4*)(Wp + s*128 + i0 + 4);
          const float4 k4 = *(const float4*)(kfp + s*128 + j0);
          float wv[8] = {wa.x,wa.y,wa.z,wa.w,wb.x,wb.y,wb.z,wb.w};
          float kv[4] = {k4.x,k4.y,k4.z,k4.w};
          #pragma unroll
          for (int a = 0; a < 8; ++a)
            #pragma unroll
            for (int q = 0; q < 4; ++q)
              acc[a][q] = fmaf(wv[a], kv[q], acc[a][q]);
        }
        #pragma unroll
        for (int a = 0; a < 8; ++a) {
          float* mp = Msh + (i0 + a)*MSP + j0;
          float4 m = *(float4*)mp;
          m.x = fmaf(C_ALPHA, acc[a][0], m.x);
          m.y = fmaf(C_ALPHA, acc[a][1], m.y);
          m.z = fmaf(C_ALPHA, acc[a][2], m.z);
          m.w = fmaf(C_ALPHA, acc[a][3], m.w);
          *(float4*)mp = m;
        }
      }
    } else {
      // waves 8-11: stage kf(c+1) + fixup P(c) (4t x 4i register tiles)
      const int t2id = tid - 512;      // 0..255
      float4 kvl[4];
      if (c < 63) {
        #pragma unroll
        for (int q = 0; q < 4; ++q)
          kvl[q] = *(const float4*)(kb + (long long)(t0 + 32)*HD + (t2id + 256*q)*4);
      }
      if (c > C0 && c <= 63) {
        const int tt = t2id >> 5;            // 0..7
        const int i0 = (t2id & 31) * 4;
        const int tb4 = tt*4;
        const float* Wp = PW + nxt*4096;
        float fac[4][4] = {};
        for (int s = 0; s < 32; ++s) {
          const float4 gx = *(const float4*)(Gxl + s*GPW + tb4);
          const float4 wp = *(const float4*)(Wp + s*128 + i0);
          float gv[4] = {gx.x,gx.y,gx.z,gx.w};
          float pv[4] = {wp.x,wp.y,wp.z,wp.w};
          #pragma unroll
          for (int a = 0; a < 4; ++a)
            #pragma unroll
            for (int q = 0; q < 4; ++q)
              fac[a][q] = fmaf(gv[a], pv[q], fac[a][q]);
        }
        float* Pp = PW + cur*4096;
        #pragma unroll
        for (int a = 0; a < 4; ++a) {
          float* pp = Pp + (tb4 + a)*128 + i0;
          float4 p = *(float4*)pp;
          p.x = fmaf(C_ALPHA, fac[a][0], p.x);
          p.y = fmaf(C_ALPHA, fac[a][1], p.y);
          p.z = fmaf(C_ALPHA, fac[a][2], p.z);
          p.w = fmaf(C_ALPHA, fac[a][3], p.w);
          *(float4*)pp = p;
        }
      }
      if (c < 63) {
        #pragma unroll
        for (int q = 0; q < 4; ++q)
          *(float4*)(kbuf + b3n*4096 + (t2id + 256*q)*4) = kvl[q];
      }
    }
    __syncthreads();
    if (c == 64) break;

    // ===== phase B (role waves, SIMD-balanced) =====
    if (w == 0) {
      // in-wave recurrence, acc[16] x 2 halves + register bridge (no spill)
      float* Pc = PW + cur*4096;
      const float* kfc = kbuf + b3c*4096;
      const float* Gc  = Gb + cur*32*GPW;
      const int l2 = lane*2;
      float2 acc[16];
      #pragma unroll
      for (int u = 0; u < 16; ++u) { acc[u].x = 0.0f; acc[u].y = 0.0f; }
      // ---- half 0: t = 0..15
      #pragma unroll
      for (int t = 0; t < 16; ++t) {
        const float2 p2 = *(const float2*)(Pc + t*128 + l2);
        const float2 k2 = *(const float2*)(kfc + t*128 + l2);
        const float it = INVB(cur, t);
        const float vx = it * fmaf(C_ALPHA, acc[t].x, p2.x);
        const float vy = it * fmaf(C_ALPHA, acc[t].y, p2.y);
        const float ex = k2.x - vx;
        const float ey = k2.y - vy;
        float e2 = fmaf(ex, ex, ey*ey);
        e2 = dpp_add_b1(e2); e2 = dpp_add_4e(e2);
        e2 = dpp_add_hm(e2); e2 = dpp_add_mr(e2);
        e2 = dpp_add_b15(e2); e2 = dpp_add_b31(e2);
        const float en2 = __int_as_float(__builtin_amdgcn_readlane(__float_as_int(e2), 63));
        const bool fire = (en2 >= TN2B(cur, t));
        const float wx = fire ? ex * it : 0.0f;
        const float wy = fire ? ey * it : 0.0f;
        float2 w2v; w2v.x = wx; w2v.y = wy;
        *(float2*)(Pc + t*128 + l2) = w2v;
        const float* gr = Gc + t*GPW;
        #pragma unroll
        for (int u4 = (t+1) & ~3; u4 < 16; u4 += 4) {
          const float4 g = *(const float4*)(gr + u4);
          acc[u4+0].x = fmaf(wx, g.x, acc[u4+0].x); acc[u4+0].y = fmaf(wy, g.x, acc[u4+0].y);
          acc[u4+1].x = fmaf(wx, g.y, acc[u4+1].x); acc[u4+1].y = fmaf(wy, g.y, acc[u4+1].y);
          acc[u4+2].x = fmaf(wx, g.z, acc[u4+2].x); acc[u4+2].y = fmaf(wy, g.z, acc[u4+2].y);
          acc[u4+3].x = fmaf(wx, g.w, acc[u4+3].x); acc[u4+3].y = fmaf(wy, g.w, acc[u4+3].y);
        }
      }
      // ---- bridge: acc[u] = sum_{s<16} w2[s] * G[s][16+u]  (G symmetric)
      #pragma unroll
      for (int u = 0; u < 16; ++u) { acc[u].x = 0.0f; acc[u].y = 0.0f; }
      #pragma unroll
      for (int s = 0; s < 16; ++s) {
        const float2 ws = *(const float2*)(Pc + s*128 + l2);
        const float* gs = Gc + s*GPW + 16;
        #pragma unroll
        for (int u4 = 0; u4 < 16; u4 += 4) {
          const float4 g = *(const float4*)(gs + u4);
          acc[u4+0].x = fmaf(ws.x, g.x, acc[u4+0].x); acc[u4+0].y = fmaf(ws.y, g.x, acc[u4+0].y);
          acc[u4+1].x = fmaf(ws.x, g.y, acc[u4+1].x); acc[u4+1].y = fmaf(ws.y, g.y, acc[u4+1].y);
          acc[u4+2].x = fmaf(ws.x, g.z, acc[u4+2].x); acc[u4+2].y = fmaf(ws.y, g.z, acc[u4+2].y);
          acc[u4+3].x = fmaf(ws.x, g.w, acc[u4+3].x); acc[u4+3].y = fmaf(ws.y, g.w, acc[u4+3].y);
        }
      }
      // ---- half 1: t = 16..31
      #pragma unroll
      for (int t = 16; t < 32; ++t) {
        const int tt = t - 16;
        const float2 p2 = *(const float2*)(Pc + t*128 + l2);
        const float2 k2 = *(const float2*)(kfc + t*128 + l2);
        const float it = INVB(cur, t);
        const float vx = it * fmaf(C_ALPHA, acc[tt].x, p2.x);
        const float vy = it * fmaf(C_ALPHA, acc[tt].y, p2.y);
        const float ex = k2.x - vx;
        const float ey = k2.y - vy;
        float e2 = fmaf(ex, ex, ey*ey);
        e2 = dpp_add_b1(e2); e2 = dpp_add_4e(e2);
        e2 = dpp_add_hm(e2); e2 = dpp_add_mr(e2);
        e2 = dpp_add_b15(e2); e2 = dpp_add_b31(e2);
        const float en2 = __int_as_float(__builtin_amdgcn_readlane(__float_as_int(e2), 63));
        const bool fire = (en2 >= TN2B(cur, t)) && (t0 + t < NSTEP);
        const float wx = fire ? ex * it : 0.0f;
        const float wy = fire ? ey * it : 0.0f;
        float2 w2v; w2v.x = wx; w2v.y = wy;
        *(float2*)(Pc + t*128 + l2) = w2v;
        const float* gr = Gc + t*GPW + 16;
        #pragma unroll
        for (int u4 = (tt+1) & ~3; u4 < 16; u4 += 4) {
          const float4 g = *(const float4*)(gr + u4);
          acc[u4+0].x = fmaf(wx, g.x, acc[u4+0].x); acc[u4+0].y = fmaf(wy, g.x, acc[u4+0].y);
          acc[u4+1].x = fmaf(wx, g.y, acc[u4+1].x); acc[u4+1].y = fmaf(wy, g.y, acc[u4+1].y);
          acc[u4+2].x = fmaf(wx, g.z, acc[u4+2].x); acc[u4+2].y = fmaf(wy, g.z, acc[u4+2].y);
          acc[u4+3].x = fmaf(wx, g.w, acc[u4+3].x); acc[u4+3].y = fmaf(wy, g.w, acc[u4+3].y);
        }
      }
    } else if (c < 63) {
      // SIMD-balanced role map:
      //  P_pre shares: w4->0, w8->1 (S0); w1,w5,w9 -> 2,3,4 (S1);
      //                w2,w6,w10 -> 5,6,7 (S2)
      //  S3: w3 = G h0, w7 = G h1, w11 = Gx h0 + Gx h1
      //  norms: on w4 after its P_pre share.
      int p;
      switch (w) {
        case 4:  p = 0; break;  case 8:  p = 1; break;
        case 1:  p = 2; break;  case 5:  p = 3; break;  case 9:  p = 4; break;
        case 2:  p = 5; break;  case 6:  p = 6; break;  case 10: p = 7; break;
        default: p = -1;
      }
      if (p >= 0) {
        // P_pre(c+1) share: t' in [4p,4p+4), all 128 i
        const float* kfn = kbuf + b3n*4096;
        const int tb4 = p*4;
        const int ib = lane & 31, ih = lane >> 5;
        float pa[4][2] = {};
        for (int j4 = 0; j4 < 32; ++j4) {
          float4 kv[4], mv[2];
          #pragma unroll
          for (int ss = 0; ss < 4; ++ss)
            kv[ss] = *(const float4*)(kfn + (tb4+ss)*128 + j4*4);
          #pragma unroll
          for (int r = 0; r < 2; ++r)
            mv[r] = *(const float4*)(Msh + (ib + 32*(ih + 2*r))*MSP + j4*4);
          #pragma unroll
          for (int ss = 0; ss < 4; ++ss)
            #pragma unroll
            for (int r = 0; r < 2; ++r) {
              pa[ss][r] = fmaf(kv[ss].x, mv[r].x, pa[ss][r]);
              pa[ss][r] = fmaf(kv[ss].y, mv[r].y, pa[ss][r]);
              pa[ss][r] = fmaf(kv[ss].z, mv[r].z, pa[ss][r]);
              pa[ss][r] = fmaf(kv[ss].w, mv[r].w, pa[ss][r]);
            }
        }
        float* Pp = PW + nxt*4096;
        #pragma unroll
        for (int ss = 0; ss < 4; ++ss)
          #pragma unroll
          for (int r = 0; r < 2; ++r)
            Pp[(tb4+ss)*128 + ib + 32*(ih + 2*r)] = pa[ss][r];
        if (w == 4) {
          // norms(c+1) (2 lanes per token)
          const float* kn = kbuf + b3n*4096;
          const int tok = lane >> 1, hh = lane & 1;
          float ss2 = 0.0f;
          #pragma unroll
          for (int q = 0; q < 16; ++q) {
            const int cq = (q + lane) & 15;
            float4 v = *(const float4*)(kn + tok*128 + hh*64 + cq*4);
            ss2 = fmaf(v.x,v.x,ss2); ss2 = fmaf(v.y,v.y,ss2);
            ss2 = fmaf(v.z,v.z,ss2); ss2 = fmaf(v.w,v.w,ss2);
          }
          ss2 += __shfl_xor(ss2, 1);
          if (hh == 0) {
            const float n = sqrtf(ss2);
            INVB(nxt, tok) = 1.0f / fmaxf(n, C_NEPS);
            const float th = C_THMIN + C_THSPAN * (1.0f - (float)(t0 + 32 + tok) / 2047.0f);
            const float tn = th * n;
            TN2B(nxt, tok) = tn * tn;
          }
        }
      } else if (w == 3) {
        gram_half(kbuf + b3n*4096, kbuf + b3n*4096, Gb + nxt*32*GPW, 0, lane);
      } else if (w == 7) {
        gram_half(kbuf + b3n*4096, kbuf + b3n*4096, Gb + nxt*32*GPW, 1, lane);
      } else {
        // w == 11: Gx(c,c+1) both halves
        gram_half(kbuf + b3c*4096, kbuf + b3n*4096, Gxl, 0, lane);
        gram_half(kbuf + b3c*4096, kbuf + b3n*4096, Gxl, 1, lane);
      }
    }
    __syncthreads();
  }

  // store M
  for (int u = tid; u < 4096; u += NT) {
    const int i = u >> 5, q = u & 31;
    *(float4*)(Mg + (long long)b*16384 + i*128 + q*4) =
        *(const float4*)(Msh + i*MSP + q*4);
  }
}

// ---------------------------------------------------------------------------
// K4a: read = M @ q ; rr = read @ rp_w + rp_b     (64 blocks x 128 threads)
// ---------------------------------------------------------------------------
extern "C" __global__ __launch_bounds__(128, 1)
void k_read(const float* __restrict__ keys, const float* __restrict__ Mg,
            const float* __restrict__ rpw, const float* __restrict__ rpb,
            float* __restrict__ rr)
{
  __shared__ float qv[128];
  __shared__ float rd[128];
  const int b = blockIdx.x, tid = threadIdx.x;
  qv[tid] = keys[((long long)b*LD + (LD-1))*HD + tid];
  __syncthreads();
  float acc = 0.0f;
  const float* Mrow = Mg + (long long)b*16384 + (long long)tid*128;
  for (int j4 = 0; j4 < 32; ++j4) {
    float4 m = *(const float4*)(Mrow + j4*4);
    acc = fmaf(m.x, qv[j4*4+0], acc);
    acc = fmaf(m.y, qv[j4*4+1], acc);
    acc = fmaf(m.z, qv[j4*4+2], acc);
    acc = fmaf(m.w, qv[j4*4+3], acc);
  }
  rd[tid] = acc;
  __syncthreads();
  float a2 = rpb[tid];
  for (int k = 0; k < 128; ++k) a2 = fmaf(rd[k], rpw[k*128 + tid], a2);
  rr[b*128 + tid] = a2;
}

// ---------------------------------------------------------------------------
// K4b: out[b][v] = rr[b] . out_w[:,v] + out_b[v]   (250 blocks x 256 threads)
// ---------------------------------------------------------------------------
extern "C" __global__ __launch_bounds__(256, 1)
void k_out(const float* __restrict__ rr, const float* __restrict__ outw,
           const float* __restrict__ outb, float* __restrict__ out)
{
  __shared__ float rl[64*128];
  const int tid = threadIdx.x;
  for (int u = tid; u < 8192; u += 256) rl[u] = rr[u];
  __syncthreads();
  const int v = blockIdx.x*128 + (tid & 127);
  const int bg = tid >> 7;
  const float ob = outb[v];
  float acc[32];
  #pragma unroll
  for (int bb = 0; bb < 32; ++bb) acc[bb] = 0.0f;
  for (int h = 0; h < 128; ++h) {
    const float wv = outw[(long long)h*VD + v];
    #pragma unroll
    for (int bb = 0; bb < 32; ++bb)
      acc[bb] = fmaf(rl[(bg*32 + bb)*128 + h], wv, acc[bb]);
  }
  #pragma unroll
  for (int bb = 0; bb < 32; ++bb)
    out[(long long)(bg*32 + bb)*VD + v] = acc[bb] + ob;
}

// ---------------------------------------------------------------------------
extern "C" void kernel_launch(void* const* d_in, const int* in_sizes, int n_in,
                              void* d_out, int out_size, void* d_ws, size_t ws_size,
                              hipStream_t stream)
{
  const int*   seq   = (const int*)d_in[0];
  const float* embed = (const float*)d_in[1];
  const float* w1    = (const float*)d_in[2];
  const float* b1    = (const float*)d_in[3];
  const float* w2    = (const float*)d_in[4];
  const float* b2    = (const float*)d_in[5];
  const float* ln_g  = (const float*)d_in[6];
  const float* ln_b  = (const float*)d_in[7];
  const float* kp_w  = (const float*)d_in[8];
  const float* rp_w  = (const float*)d_in[9];
  const float* rp_b  = (const float*)d_in[10];
  const float* out_w = (const float*)d_in[11];
  const float* out_b = (const float*)d_in[12];
  float* out = (float*)d_out;

  char* ws = (char*)d_ws;
  float* keys = (float*)ws;                               // 64 MiB
  float* Mg   = (float*)(ws + 67108864);                  // 4 MiB
  float* rr   = (float*)(ws + 67108864 + 4194304);        // 32 KiB

  hipLaunchKernelGGL(k_tokens, dim3(64*TBLK), dim3(512), 137216, stream,
                     seq, embed, w1, b1, w2, b2, ln_g, ln_b, kp_w, keys);
  hipLaunchKernelGGL(k_scan, dim3(64), dim3(768), 163328, stream, keys, Mg);
  hipLaunchKernelGGL(k_read, dim3(64), dim3(128), 0, stream, keys, Mg, rp_w, rp_b, rr);
  hipLaunchKernelGGL(k_out, dim3(250), dim3(256), 0, stream, rr, out_w, out_b, out);
}

// Round 14
// 768.315 us; speedup vs baseline: 1.2621x; 1.0113x over previous
//
#include <hip/hip_runtime.h>

#define HD 128
#define LD 2048
#define BD 64
#define VD 32000
#define NSTEP 2047   // L-1 scan steps, t = 0..2046

// f32 constants exactly matching the reference's f32-cast scalars
#define C_ALPHA  0.05f
#define C_THMIN  0.4f
#define C_THSPAN 1.1f
#define C_NEPS   1e-12f
#define C_LNEPS  1e-5f

// ---------------------------------------------------------------------------
// K1: fused embed-gather + MLP + LayerNorm + keys=hn@kp (round-13 exact).
// LDS-bandwidth-bound at ~1.5 B/FMA (measured: thread count 256 vs 512 made
// no difference); ~180 us. Only tokens >= 896 are live (first fire t=931).
// ---------------------------------------------------------------------------
#define HSP 132
#define W1P 68
#define W2P 132
#define ATP 68
#define TOK0 896
#define TBLK 9

extern "C" __global__ __launch_bounds__(512, 1)
void k_tokens(const int* __restrict__ seq, const float* __restrict__ embed,
              const float* __restrict__ w1, const float* __restrict__ b1,
              const float* __restrict__ w2, const float* __restrict__ b2,
              const float* __restrict__ lng, const float* __restrict__ lnb,
              const float* __restrict__ kp, float* __restrict__ keys)
{
  extern __shared__ float sm[];
  float* hs = sm;                 // [128][HSP]  h, later hn
  float* wt = sm + 128*HSP;       // [128][W1P] (w1 tile) or [64][W2P] (w2/kp)
  float* at = wt + 128*W1P;       // [128][ATP]  relu tile
  const int tid = threadIdx.x;
  const int bb  = blockIdx.x / TBLK;
  const int rel = blockIdx.x % TBLK;
  const long long tokBase = (long long)bb * LD + TOK0 + rel * 128;

  // ---- gather h = embed[seq]
  for (int u = tid; u < 128*32; u += 512) {
    const int tok = u >> 5, seg = u & 31;
    const int s = seq[tokBase + tok];
    *(float4*)(hs + tok*HSP + seg*4) =
        *(const float4*)(embed + (long long)s*HD + seg*4);
  }
  __syncthreads();

  const int tg = tid >> 5;   // token group 0..15: tok = tg + 16*r, r=0..7
  const int ig = tid & 31;   // column group 0..31

  float xacc[8][4] = {};     // x (MLP out): 8 tok x 4 i (i = ig*4+q)

  for (int jt = 0; jt < 4; ++jt) {
    // stage w1 tile [128 i][64 j]
    for (int u = tid; u < 128*16; u += 512) {
      const int i = u >> 4, q = u & 15;
      *(float4*)(wt + i*W1P + q*4) =
          *(const float4*)(w1 + (long long)i*256 + jt*64 + q*4);
    }
    __syncthreads();
    // a-tile = relu(h @ w1tile + b1): thread = 8 tok x 2 j  (j = ig*2+c)
    {
      float aa[8][2];
      float b1v[2];
      b1v[0] = b1[jt*64 + ig*2];
      b1v[1] = b1[jt*64 + ig*2 + 1];
      #pragma unroll
      for (int r = 0; r < 8; ++r) { aa[r][0] = b1v[0]; aa[r][1] = b1v[1]; }
      #pragma unroll 4
      for (int i4 = 0; i4 < 32; ++i4) {
        float2 wc[4];
        #pragma unroll
        for (int d = 0; d < 4; ++d)
          wc[d] = *(const float2*)(wt + (i4*4 + d)*W1P + ig*2);
        #pragma unroll
        for (int r = 0; r < 8; ++r) {
          float4 hv = *(const float4*)(hs + (tg + 16*r)*HSP + i4*4);
          aa[r][0] = fmaf(hv.x, wc[0].x, aa[r][0]);
          aa[r][0] = fmaf(hv.y, wc[1].x, aa[r][0]);
          aa[r][0] = fmaf(hv.z, wc[2].x, aa[r][0]);
          aa[r][0] = fmaf(hv.w, wc[3].x, aa[r][0]);
          aa[r][1] = fmaf(hv.x, wc[0].y, aa[r][1]);
          aa[r][1] = fmaf(hv.y, wc[1].y, aa[r][1]);
          aa[r][1] = fmaf(hv.z, wc[2].y, aa[r][1]);
          aa[r][1] = fmaf(hv.w, wc[3].y, aa[r][1]);
        }
      }
      #pragma unroll
      for (int r = 0; r < 8; ++r) {
        float2 o;
        o.x = fmaxf(aa[r][0], 0.0f);
        o.y = fmaxf(aa[r][1], 0.0f);
        *(float2*)(at + (tg + 16*r)*ATP + ig*2) = o;
      }
    }
    __syncthreads();
    // stage w2 tile [64 k][128 i]
    for (int u = tid; u < 64*32; u += 512) {
      const int k = u >> 5, q = u & 31;
      *(float4*)(wt + k*W2P + q*4) =
          *(const float4*)(w2 + (long long)(jt*64 + k)*128 + q*4);
    }
    __syncthreads();
    // x += a-tile @ w2tile: thread = 8 tok x 4 i
    #pragma unroll 2
    for (int k4 = 0; k4 < 16; ++k4) {
      float4 wr[4];
      #pragma unroll
      for (int d = 0; d < 4; ++d)
        wr[d] = *(const float4*)(wt + (k4*4 + d)*W2P + ig*4);
      #pragma unroll
      for (int r = 0; r < 8; ++r) {
        float4 av = *(const float4*)(at + (tg + 16*r)*ATP + k4*4);
        xacc[r][0] = fmaf(av.x, wr[0].x, xacc[r][0]);
        xacc[r][0] = fmaf(av.y, wr[1].x, xacc[r][0]);
        xacc[r][0] = fmaf(av.z, wr[2].x, xacc[r][0]);
        xacc[r][0] = fmaf(av.w, wr[3].x, xacc[r][0]);
        xacc[r][1] = fmaf(av.x, wr[0].y, xacc[r][1]);
        xacc[r][1] = fmaf(av.y, wr[1].y, xacc[r][1]);
        xacc[r][1] = fmaf(av.z, wr[2].y, xacc[r][1]);
        xacc[r][1] = fmaf(av.w, wr[3].y, xacc[r][1]);
        xacc[r][2] = fmaf(av.x, wr[0].z, xacc[r][2]);
        xacc[r][2] = fmaf(av.y, wr[1].z, xacc[r][2]);
        xacc[r][2] = fmaf(av.z, wr[2].z, xacc[r][2]);
        xacc[r][2] = fmaf(av.w, wr[3].z, xacc[r][2]);
        xacc[r][3] = fmaf(av.x, wr[0].w, xacc[r][3]);
        xacc[r][3] = fmaf(av.y, wr[1].w, xacc[r][3]);
        xacc[r][3] = fmaf(av.z, wr[2].w, xacc[r][3]);
        xacc[r][3] = fmaf(av.w, wr[3].w, xacc[r][3]);
      }
    }
    __syncthreads();
  }

  // ---- x = h + (x + b2); LayerNorm (32 lanes share a token); hn -> hs
  {
    float b2v[4], gv[4], bv[4];
    #pragma unroll
    for (int q = 0; q < 4; ++q) {
      b2v[q] = b2[ig*4 + q]; gv[q] = lng[ig*4 + q]; bv[q] = lnb[ig*4 + q];
    }
    #pragma unroll
    for (int r = 0; r < 8; ++r) {
      const int row = (tg + 16*r)*HSP + ig*4;
      float4 h0 = *(const float4*)(hs + row);
      float xr[4];
      xr[0] = h0.x + (xacc[r][0] + b2v[0]);
      xr[1] = h0.y + (xacc[r][1] + b2v[1]);
      xr[2] = h0.z + (xacc[r][2] + b2v[2]);
      xr[3] = h0.w + (xacc[r][3] + b2v[3]);
      float s = xr[0] + xr[1] + xr[2] + xr[3];
      s += __shfl_xor(s, 1, 32);  s += __shfl_xor(s, 2, 32);
      s += __shfl_xor(s, 4, 32);  s += __shfl_xor(s, 8, 32);
      s += __shfl_xor(s, 16, 32);
      const float mu = s * 0.0078125f;
      float vs = 0.0f;
      #pragma unroll
      for (int q = 0; q < 4; ++q) { float d = xr[q]-mu; vs = fmaf(d, d, vs); }
      vs += __shfl_xor(vs, 1, 32);  vs += __shfl_xor(vs, 2, 32);
      vs += __shfl_xor(vs, 4, 32);  vs += __shfl_xor(vs, 8, 32);
      vs += __shfl_xor(vs, 16, 32);
      const float rstd = 1.0f / sqrtf(vs * 0.0078125f + C_LNEPS);
      float4 o;
      o.x = (xr[0]-mu)*rstd*gv[0] + bv[0];
      o.y = (xr[1]-mu)*rstd*gv[1] + bv[1];
      o.z = (xr[2]-mu)*rstd*gv[2] + bv[2];
      o.w = (xr[3]-mu)*rstd*gv[3] + bv[3];
      *(float4*)(hs + row) = o;
    }
  }
  __syncthreads();

  // ---- keys = hn @ kp
  {
    float ky[8][4] = {};
    for (int kt = 0; kt < 2; ++kt) {
      for (int u = tid; u < 64*32; u += 512) {
        const int k = u >> 5, q = u & 31;
        *(float4*)(wt + k*W2P + q*4) =
            *(const float4*)(kp + (long long)(kt*64 + k)*128 + q*4);
      }
      __syncthreads();
      #pragma unroll 2
      for (int k4 = 0; k4 < 16; ++k4) {
        float4 wr[4];
        #pragma unroll
        for (int d = 0; d < 4; ++d)
          wr[d] = *(const float4*)(wt + (k4*4 + d)*W2P + ig*4);
        #pragma unroll
        for (int r = 0; r < 8; ++r) {
          float4 hv = *(const float4*)(hs + (tg + 16*r)*HSP + kt*64 + k4*4);
          ky[r][0] = fmaf(hv.x, wr[0].x, ky[r][0]);
          ky[r][0] = fmaf(hv.y, wr[1].x, ky[r][0]);
          ky[r][0] = fmaf(hv.z, wr[2].x, ky[r][0]);
          ky[r][0] = fmaf(hv.w, wr[3].x, ky[r][0]);
          ky[r][1] = fmaf(hv.x, wr[0].y, ky[r][1]);
          ky[r][1] = fmaf(hv.y, wr[1].y, ky[r][1]);
          ky[r][1] = fmaf(hv.z, wr[2].y, ky[r][1]);
          ky[r][1] = fmaf(hv.w, wr[3].y, ky[r][1]);
          ky[r][2] = fmaf(hv.x, wr[0].z, ky[r][2]);
          ky[r][2] = fmaf(hv.y, wr[1].z, ky[r][2]);
          ky[r][2] = fmaf(hv.z, wr[2].z, ky[r][2]);
          ky[r][2] = fmaf(hv.w, wr[3].z, ky[r][2]);
          ky[r][3] = fmaf(hv.x, wr[0].w, ky[r][3]);
          ky[r][3] = fmaf(hv.y, wr[1].w, ky[r][3]);
          ky[r][3] = fmaf(hv.z, wr[2].w, ky[r][3]);
          ky[r][3] = fmaf(hv.w, wr[3].w, ky[r][3]);
        }
      }
      __syncthreads();
    }
    #pragma unroll
    for (int r = 0; r < 8; ++r) {
      const long long g = tokBase + tg + 16*r;
      float4 o;
      o.x = ky[r][0]; o.y = ky[r][1]; o.z = ky[r][2]; o.w = ky[r][3];
      *(float4*)(keys + g*HD + ig*4) = o;
    }
  }
}

// ---------------------------------------------------------------------------
// K3: the scan — ROUND-11 exact (best measured: 462 us). 64 blocks x 768
// threads (12 waves, 3/SIMD). Phase A: U (waves 0-7, 8ix4j reg tiles,
// kf(c-1) from LDS triple-buffer); fixup+staging (waves 8-11). Phase B:
// S0 = recurrence(w0) + 2 P_pre(w4,w8) (+norms on w4); S1/S2 = 6 P_pre;
// S3: w3=G h0, w7=G h1, w11=Gx h0+h1. 2 barriers/chunk. Chunks < 29 dead.
// Dynamic LDS = 163328 B.
// ---------------------------------------------------------------------------
#define C0 29
#define MSP 132   // Msh pitch
#define GPW 36    // G/Gx pitch
#define NT 768

#define INVB(buf,tok) Gxl[(tok)*GPW + 32 + (buf)]
#define TN2B(buf,tok) Gxl[(tok)*GPW + 34 + (buf)]

__device__ __forceinline__ float dpp_add_b1(float x){int y=__builtin_amdgcn_update_dpp(0,__float_as_int(x),0xB1,0xf,0xf,true);return x+__int_as_float(y);}
__device__ __forceinline__ float dpp_add_4e(float x){int y=__builtin_amdgcn_update_dpp(0,__float_as_int(x),0x4E,0xf,0xf,true);return x+__int_as_float(y);}
__device__ __forceinline__ float dpp_add_hm(float x){int y=__builtin_amdgcn_update_dpp(0,__float_as_int(x),0x141,0xf,0xf,true);return x+__int_as_float(y);}
__device__ __forceinline__ float dpp_add_mr(float x){int y=__builtin_amdgcn_update_dpp(0,__float_as_int(x),0x140,0xf,0xf,true);return x+__int_as_float(y);}
__device__ __forceinline__ float dpp_add_b15(float x){int y=__builtin_amdgcn_update_dpp(0,__float_as_int(x),0x142,0xf,0xf,true);return x+__int_as_float(y);}
__device__ __forceinline__ float dpp_add_b31(float x){int y=__builtin_amdgcn_update_dpp(0,__float_as_int(x),0x143,0xf,0xf,true);return x+__int_as_float(y);}

// G / Gx half-tile: 32 s-rows x 16 t-cols, one wave. Row pitch 128 with
// per-lane column rotation (2-way banks). Stride-8 row blocking.
__device__ __forceinline__ void gram_half(const float* bufS, const float* bufT,
                                          float* dst, int half, int lane)
{
  const int sq = lane & 7, tq = lane >> 3;
  float ga[4][2] = {};
  for (int j4 = 0; j4 < 32; ++j4) {
    const int col = ((j4 + lane) & 31) * 4;
    float4 sv[4], tv[2];
    #pragma unroll
    for (int r = 0; r < 4; ++r)
      sv[r] = *(const float4*)(bufS + (sq + 8*r)*128 + col);
    #pragma unroll
    for (int q = 0; q < 2; ++q)
      tv[q] = *(const float4*)(bufT + (half*16 + tq*2 + q)*128 + col);
    #pragma unroll
    for (int r = 0; r < 4; ++r)
      #pragma unroll
      for (int q = 0; q < 2; ++q) {
        ga[r][q] = fmaf(sv[r].x, tv[q].x, ga[r][q]);
        ga[r][q] = fmaf(sv[r].y, tv[q].y, ga[r][q]);
        ga[r][q] = fmaf(sv[r].z, tv[q].z, ga[r][q]);
        ga[r][q] = fmaf(sv[r].w, tv[q].w, ga[r][q]);
      }
  }
  #pragma unroll
  for (int r = 0; r < 4; ++r)
    #pragma unroll
    for (int q = 0; q < 2; ++q)
      dst[(sq + 8*r)*GPW + half*16 + tq*2 + q] = ga[r][q];
}

extern "C" __global__ __launch_bounds__(768)
void k_scan(const float* __restrict__ keys, float* __restrict__ Mg)
{
  extern __shared__ float sm[];
  float* Msh  = sm;                    // [128][132]           16896
  float* kbuf = Msh + 128*MSP;         // [3][32][128]         12288
  float* PW   = kbuf + 3*4096;         // [2][32][128]          8192
  float* Gb   = PW + 2*4096;           // [2][32][36]           2304
  float* Gxl  = Gb + 2*32*GPW;         // [32][36] (+inv/tn2)   1152
  // total 40832 floats = 163328 B

  const int tid  = threadIdx.x;
  const int lane = tid & 63;
  const int w    = tid >> 6;
  const int b    = blockIdx.x;
  const float* kb = keys + (long long)b * LD * HD;

  // ---------------- prologue ----------------
  for (int u = tid; u < 128*MSP; u += NT) Msh[u] = 0.0f;
  for (int u = tid; u < 4096; u += NT) PW[(C0&1)*4096 + u] = 0.0f;  // P(C0)=0
  {
    const int b30 = C0 % 3;   // = 2
    for (int u = tid; u < 1024; u += NT)
      *(float4*)(kbuf + b30*4096 + u*4) =
          *(const float4*)(kb + (long long)(C0*32)*HD + u*4);
  }
  __syncthreads();
  {
    const float* kc = kbuf + (C0%3)*4096;
    for (int u = tid; u < 1024; u += NT) {
      const int s = u >> 5, t = u & 31;
      float a = 0.0f;
      for (int j4 = 0; j4 < 32; ++j4) {
        const int col = ((j4 + tid) & 31) * 4;
        float4 sv = *(const float4*)(kc + s*128 + col);
        float4 tv = *(const float4*)(kc + t*128 + col);
        a = fmaf(sv.x,tv.x,a); a = fmaf(sv.y,tv.y,a);
        a = fmaf(sv.z,tv.z,a); a = fmaf(sv.w,tv.w,a);
      }
      Gb[(C0&1)*32*GPW + s*GPW + t] = a;
    }
  }
  if (tid < 256) {
    const int tok = tid >> 3, pp = tid & 7;
    const float* kc = kbuf + (C0%3)*4096;
    float ss = 0.0f;
    #pragma unroll
    for (int q = 0; q < 4; ++q) {
      float4 v = *(const float4*)(kc + tok*128 + pp*16 + q*4);
      ss = fmaf(v.x,v.x,ss); ss = fmaf(v.y,v.y,ss);
      ss = fmaf(v.z,v.z,ss); ss = fmaf(v.w,v.w,ss);
    }
    ss += __shfl_xor(ss,1,8); ss += __shfl_xor(ss,2,8); ss += __shfl_xor(ss,4,8);
    if (pp == 0) {
      const float n = sqrtf(ss);
      INVB(C0&1, tok) = 1.0f / fmaxf(n, C_NEPS);
      const float th = C_THMIN + C_THSPAN * (1.0f - (float)(C0*32 + tok) / 2047.0f);
      const float tn = th * n;
      TN2B(C0&1, tok) = tn * tn;
    }
  }
  __syncthreads();

  // ---------------- main loop ----------------
  for (int c = C0; c <= 64; ++c) {
    const int cur = c & 1, nxt = cur ^ 1;
    const int b3c = c % 3;            // kf(c)
    const int b3n = (c + 1) % 3;      // kf(c+1) dest
    const int b3p = (c + 2) % 3;      // == (c-1)%3, kf(c-1)
    const int t0 = c * 32;

    // ===== phase A =====
    if (w < 8) {
      // U(c-1): M += alpha * W2_{c-1}^T kf_{c-1}   (8i x 4j register tiles)
      if (c > C0) {
        const int it = tid >> 5;       // 0..15
        const int jt = tid & 31;       // 0..31
        const int i0 = it*8, j0 = jt*4;
        const float* Wp  = PW + nxt*4096;
        const float* kfp = kbuf + b3p*4096;
        float acc[8][4] = {};
        for (int s = 0; s < 32; ++s) {
          const float4 wa = *(const float4*)(Wp + s*128 + i0);
          const float4 wb = *(const float4*)(Wp + s*128 + i0 + 4);
          const float4 k4 = *(const float4*)(kfp + s*128 + j0);
          float wv[8] = {wa.x,wa.y,wa.z,wa.w,wb.x,wb.y,wb.z,wb.w};
          float kv[4] = {k4.x,k4.y,k4.z,k4.w};
          #pragma unroll
          for (int a = 0; a < 8; ++a)
            #pragma unroll
            for (int q = 0; q < 4; ++q)
              acc[a][q] = fmaf(wv[a], kv[q], acc[a][q]);
        }
        #pragma unroll
        for (int a = 0; a < 8; ++a) {
          float* mp = Msh + (i0 + a)*MSP + j0;
          float4 m = *(float4*)mp;
          m.x = fmaf(C_ALPHA, acc[a][0], m.x);
          m.y = fmaf(C_ALPHA, acc[a][1], m.y);
          m.z = fmaf(C_ALPHA, acc[a][2], m.z);
          m.w = fmaf(C_ALPHA, acc[a][3], m.w);
          *(float4*)mp = m;
        }
      }
    } else {
      // waves 8-11: stage kf(c+1) + fixup P(c) (4t x 4i register tiles)
      const int t2id = tid - 512;      // 0..255
      float4 kvl[4];
      if (c < 63) {
        #pragma unroll
        for (int q = 0; q < 4; ++q)
          kvl[q] = *(const float4*)(kb + (long long)(t0 + 32)*HD + (t2id + 256*q)*4);
      }
      if (c > C0 && c <= 63) {
        const int tt = t2id >> 5;            // 0..7
        const int i0 = (t2id & 31) * 4;
        const int tb4 = tt*4;
        const float* Wp = PW + nxt*4096;
        float fac[4][4] = {};
        for (int s = 0; s < 32; ++s) {
          const float4 gx = *(const float4*)(Gxl + s*GPW + tb4);
          const float4 wp = *(const float4*)(Wp + s*128 + i0);
          float gv[4] = {gx.x,gx.y,gx.z,gx.w};
          float pv[4] = {wp.x,wp.y,wp.z,wp.w};
          #pragma unroll
          for (int a = 0; a < 4; ++a)
            #pragma unroll
            for (int q = 0; q < 4; ++q)
              fac[a][q] = fmaf(gv[a], pv[q], fac[a][q]);
        }
        float* Pp = PW + cur*4096;
        #pragma unroll
        for (int a = 0; a < 4; ++a) {
          float* pp = Pp + (tb4 + a)*128 + i0;
          float4 p = *(float4*)pp;
          p.x = fmaf(C_ALPHA, fac[a][0], p.x);
          p.y = fmaf(C_ALPHA, fac[a][1], p.y);
          p.z = fmaf(C_ALPHA, fac[a][2], p.z);
          p.w = fmaf(C_ALPHA, fac[a][3], p.w);
          *(float4*)pp = p;
        }
      }
      if (c < 63) {
        #pragma unroll
        for (int q = 0; q < 4; ++q)
          *(float4*)(kbuf + b3n*4096 + (t2id + 256*q)*4) = kvl[q];
      }
    }
    __syncthreads();
    if (c == 64) break;

    // ===== phase B (role waves, SIMD-balanced) =====
    if (w == 0) {
      // in-wave recurrence, acc[16] x 2 halves + register bridge (no spill)
      float* Pc = PW + cur*4096;
      const float* kfc = kbuf + b3c*4096;
      const float* Gc  = Gb + cur*32*GPW;
      const int l2 = lane*2;
      float2 acc[16];
      #pragma unroll
      for (int u = 0; u < 16; ++u) { acc[u].x = 0.0f; acc[u].y = 0.0f; }
      // ---- half 0: t = 0..15
      #pragma unroll
      for (int t = 0; t < 16; ++t) {
        const float2 p2 = *(const float2*)(Pc + t*128 + l2);
        const float2 k2 = *(const float2*)(kfc + t*128 + l2);
        const float it = INVB(cur, t);
        const float vx = it * fmaf(C_ALPHA, acc[t].x, p2.x);
        const float vy = it * fmaf(C_ALPHA, acc[t].y, p2.y);
        const float ex = k2.x - vx;
        const float ey = k2.y - vy;
        float e2 = fmaf(ex, ex, ey*ey);
        e2 = dpp_add_b1(e2); e2 = dpp_add_4e(e2);
        e2 = dpp_add_hm(e2); e2 = dpp_add_mr(e2);
        e2 = dpp_add_b15(e2); e2 = dpp_add_b31(e2);
        const float en2 = __int_as_float(__builtin_amdgcn_readlane(__float_as_int(e2), 63));
        const bool fire = (en2 >= TN2B(cur, t));
        const float wx = fire ? ex * it : 0.0f;
        const float wy = fire ? ey * it : 0.0f;
        float2 w2v; w2v.x = wx; w2v.y = wy;
        *(float2*)(Pc + t*128 + l2) = w2v;
        const float* gr = Gc + t*GPW;
        #pragma unroll
        for (int u4 = (t+1) & ~3; u4 < 16; u4 += 4) {
          const float4 g = *(const float4*)(gr + u4);
          acc[u4+0].x = fmaf(wx, g.x, acc[u4+0].x); acc[u4+0].y = fmaf(wy, g.x, acc[u4+0].y);
          acc[u4+1].x = fmaf(wx, g.y, acc[u4+1].x); acc[u4+1].y = fmaf(wy, g.y, acc[u4+1].y);
          acc[u4+2].x = fmaf(wx, g.z, acc[u4+2].x); acc[u4+2].y = fmaf(wy, g.z, acc[u4+2].y);
          acc[u4+3].x = fmaf(wx, g.w, acc[u4+3].x); acc[u4+3].y = fmaf(wy, g.w, acc[u4+3].y);
        }
      }
      // ---- bridge: acc[u] = sum_{s<16} w2[s] * G[s][16+u]  (G symmetric)
      #pragma unroll
      for (int u = 0; u < 16; ++u) { acc[u].x = 0.0f; acc[u].y = 0.0f; }
      #pragma unroll
      for (int s = 0; s < 16; ++s) {
        const float2 ws = *(const float2*)(Pc + s*128 + l2);
        const float* gs = Gc + s*GPW + 16;
        #pragma unroll
        for (int u4 = 0; u4 < 16; u4 += 4) {
          const float4 g = *(const float4*)(gs + u4);
          acc[u4+0].x = fmaf(ws.x, g.x, acc[u4+0].x); acc[u4+0].y = fmaf(ws.y, g.x, acc[u4+0].y);
          acc[u4+1].x = fmaf(ws.x, g.y, acc[u4+1].x); acc[u4+1].y = fmaf(ws.y, g.y, acc[u4+1].y);
          acc[u4+2].x = fmaf(ws.x, g.z, acc[u4+2].x); acc[u4+2].y = fmaf(ws.y, g.z, acc[u4+2].y);
          acc[u4+3].x = fmaf(ws.x, g.w, acc[u4+3].x); acc[u4+3].y = fmaf(ws.y, g.w, acc[u4+3].y);
        }
      }
      // ---- half 1: t = 16..31
      #pragma unroll
      for (int t = 16; t < 32; ++t) {
        const int tt = t - 16;
        const float2 p2 = *(const float2*)(Pc + t*128 + l2);
        const float2 k2 = *(const float2*)(kfc + t*128 + l2);
        const float it = INVB(cur, t);
        const float vx = it * fmaf(C_ALPHA, acc[tt].x, p2.x);
        const float vy = it * fmaf(C_ALPHA, acc[tt].y, p2.y);
        const float ex = k2.x - vx;
        const float ey = k2.y - vy;
        float e2 = fmaf(ex, ex, ey*ey);
        e2 = dpp_add_b1(e2); e2 = dpp_add_4e(e2);
        e2 = dpp_add_hm(e2); e2 = dpp_add_mr(e2);
        e2 = dpp_add_b15(e2); e2 = dpp_add_b31(e2);
        const float en2 = __int_as_float(__builtin_amdgcn_readlane(__float_as_int(e2), 63));
        const bool fire = (en2 >= TN2B(cur, t)) && (t0 + t < NSTEP);
        const float wx = fire ? ex * it : 0.0f;
        const float wy = fire ? ey * it : 0.0f;
        float2 w2v; w2v.x = wx; w2v.y = wy;
        *(float2*)(Pc + t*128 + l2) = w2v;
        const float* gr = Gc + t*GPW + 16;
        #pragma unroll
        for (int u4 = (tt+1) & ~3; u4 < 16; u4 += 4) {
          const float4 g = *(const float4*)(gr + u4);
          acc[u4+0].x = fmaf(wx, g.x, acc[u4+0].x); acc[u4+0].y = fmaf(wy, g.x, acc[u4+0].y);
          acc[u4+1].x = fmaf(wx, g.y, acc[u4+1].x); acc[u4+1].y = fmaf(wy, g.y, acc[u4+1].y);
          acc[u4+2].x = fmaf(wx, g.z, acc[u4+2].x); acc[u4+2].y = fmaf(wy, g.z, acc[u4+2].y);
          acc[u4+3].x = fmaf(wx, g.w, acc[u4+3].x); acc[u4+3].y = fmaf(wy, g.w, acc[u4+3].y);
        }
      }
    } else if (c < 63) {
      // SIMD-balanced role map:
      //  P_pre shares: w4->0, w8->1 (S0); w1,w5,w9 -> 2,3,4 (S1);
      //                w2,w6,w10 -> 5,6,7 (S2)
      //  S3: w3 = G h0, w7 = G h1, w11 = Gx h0 + h1
      //  norms: on w4 after its P_pre share.
      int p;
      switch (w) {
        case 4:  p = 0; break;  case 8:  p = 1; break;
        case 1:  p = 2; break;  case 5:  p = 3; break;  case 9:  p = 4; break;
        case 2:  p = 5; break;  case 6:  p = 6; break;  case 10: p = 7; break;
        default: p = -1;
      }
      if (p >= 0) {
        // P_pre(c+1) share: t' in [4p,4p+4), all 128 i
        const float* kfn = kbuf + b3n*4096;
        const int tb4 = p*4;
        const int ib = lane & 31, ih = lane >> 5;
        float pa[4][2] = {};
        for (int j4 = 0; j4 < 32; ++j4) {
          float4 kv[4], mv[2];
          #pragma unroll
          for (int ss = 0; ss < 4; ++ss)
            kv[ss] = *(const float4*)(kfn + (tb4+ss)*128 + j4*4);
          #pragma unroll
          for (int r = 0; r < 2; ++r)
            mv[r] = *(const float4*)(Msh + (ib + 32*(ih + 2*r))*MSP + j4*4);
          #pragma unroll
          for (int ss = 0; ss < 4; ++ss)
            #pragma unroll
            for (int r = 0; r < 2; ++r) {
              pa[ss][r] = fmaf(kv[ss].x, mv[r].x, pa[ss][r]);
              pa[ss][r] = fmaf(kv[ss].y, mv[r].y, pa[ss][r]);
              pa[ss][r] = fmaf(kv[ss].z, mv[r].z, pa[ss][r]);
              pa[ss][r] = fmaf(kv[ss].w, mv[r].w, pa[ss][r]);
            }
        }
        float* Pp = PW + nxt*4096;
        #pragma unroll
        for (int ss = 0; ss < 4; ++ss)
          #pragma unroll
          for (int r = 0; r < 2; ++r)
            Pp[(tb4+ss)*128 + ib + 32*(ih + 2*r)] = pa[ss][r];
        if (w == 4) {
          // norms(c+1) (2 lanes per token)
          const float* kn = kbuf + b3n*4096;
          const int tok = lane >> 1, hh = lane & 1;
          float ss2 = 0.0f;
          #pragma unroll
          for (int q = 0; q < 16; ++q) {
            const int cq = (q + lane) & 15;
            float4 v = *(const float4*)(kn + tok*128 + hh*64 + cq*4);
            ss2 = fmaf(v.x,v.x,ss2); ss2 = fmaf(v.y,v.y,ss2);
            ss2 = fmaf(v.z,v.z,ss2); ss2 = fmaf(v.w,v.w,ss2);
          }
          ss2 += __shfl_xor(ss2, 1);
          if (hh == 0) {
            const float n = sqrtf(ss2);
            INVB(nxt, tok) = 1.0f / fmaxf(n, C_NEPS);
            const float th = C_THMIN + C_THSPAN * (1.0f - (float)(t0 + 32 + tok) / 2047.0f);
            const float tn = th * n;
            TN2B(nxt, tok) = tn * tn;
          }
        }
      } else if (w == 3) {
        gram_half(kbuf + b3n*4096, kbuf + b3n*4096, Gb + nxt*32*GPW, 0, lane);
      } else if (w == 7) {
        gram_half(kbuf + b3n*4096, kbuf + b3n*4096, Gb + nxt*32*GPW, 1, lane);
      } else {
        // w == 11: Gx(c,c+1) both halves
        gram_half(kbuf + b3c*4096, kbuf + b3n*4096, Gxl, 0, lane);
        gram_half(kbuf + b3c*4096, kbuf + b3n*4096, Gxl, 1, lane);
      }
    }
    __syncthreads();
  }

  // store M
  for (int u = tid; u < 4096; u += NT) {
    const int i = u >> 5, q = u & 31;
    *(float4*)(Mg + (long long)b*16384 + i*128 + q*4) =
        *(const float4*)(Msh + i*MSP + q*4);
  }
}

// ---------------------------------------------------------------------------
// K4a: read = M @ q ; rr = read @ rp_w + rp_b     (64 blocks x 128 threads)
// Round-14: coalesced M load into LDS (pitch 132: conflict-free float4
// reads, (tid*33+j4)%32 distinct per lane), then in-LDS dot. rpw loop
// split into 4 independent partials for ILP. Old version read Mrow with
// 512B lane stride = fully uncoalesced HBM.
// ---------------------------------------------------------------------------
extern "C" __global__ __launch_bounds__(128, 1)
void k_read(const float* __restrict__ keys, const float* __restrict__ Mg,
            const float* __restrict__ rpw, const float* __restrict__ rpb,
            float* __restrict__ rr)
{
  __shared__ float Msl[128*132];
  __shared__ float qv[128];
  __shared__ float rd[128];
  const int b = blockIdx.x, tid = threadIdx.x;
  qv[tid] = keys[((long long)b*LD + (LD-1))*HD + tid];
  for (int u = tid; u < 4096; u += 128) {
    const int i = u >> 5, q = u & 31;
    *(float4*)(Msl + i*132 + q*4) =
        *(const float4*)(Mg + (long long)b*16384 + (long long)u*4);
  }
  __syncthreads();
  float acc = 0.0f;
  const float* mr = Msl + tid*132;
  #pragma unroll 4
  for (int j4 = 0; j4 < 32; ++j4) {
    const float4 m = *(const float4*)(mr + j4*4);
    acc = fmaf(m.x, qv[j4*4+0], acc);
    acc = fmaf(m.y, qv[j4*4+1], acc);
    acc = fmaf(m.z, qv[j4*4+2], acc);
    acc = fmaf(m.w, qv[j4*4+3], acc);
  }
  rd[tid] = acc;
  __syncthreads();
  float s0 = rpb[tid], s1 = 0.0f, s2 = 0.0f, s3 = 0.0f;
  for (int k = 0; k < 128; k += 4) {
    s0 = fmaf(rd[k+0], rpw[(k+0)*128 + tid], s0);
    s1 = fmaf(rd[k+1], rpw[(k+1)*128 + tid], s1);
    s2 = fmaf(rd[k+2], rpw[(k+2)*128 + tid], s2);
    s3 = fmaf(rd[k+3], rpw[(k+3)*128 + tid], s3);
  }
  rr[b*128 + tid] = (s0 + s1) + (s2 + s3);
}

// ---------------------------------------------------------------------------
// K4b: out[b][v] = rr[b] . out_w[:,v] + out_b[v]
// Round-14: 500 blocks x 256 threads (was 250: 1 wave/SIMD, latency-bound).
// v-tile 64, batch in 4 groups of 16 -> 2 blocks/CU, 16 indep FMA chains
// per wv load, h-unroll x2. rl reads are wave-broadcast. Accumulation
// order per output unchanged (h ascending).
// ---------------------------------------------------------------------------
extern "C" __global__ __launch_bounds__(256, 1)
void k_out(const float* __restrict__ rr, const float* __restrict__ outw,
           const float* __restrict__ outb, float* __restrict__ out)
{
  __shared__ float rl[64*128];
  const int tid = threadIdx.x;
  for (int u = tid; u < 8192; u += 256) rl[u] = rr[u];
  __syncthreads();
  const int v  = blockIdx.x*64 + (tid & 63);
  const int bg = tid >> 6;   // 0..3 -> batches bg*16..+15
  const float ob = outb[v];
  const float* rbase = rl + bg*16*128;
  float acc[16];
  #pragma unroll
  for (int bb = 0; bb < 16; ++bb) acc[bb] = 0.0f;
  for (int h = 0; h < 128; h += 2) {
    const float wv0 = outw[(long long)h*VD + v];
    const float wv1 = outw[(long long)(h+1)*VD + v];
    #pragma unroll
    for (int bb = 0; bb < 16; ++bb) {
      acc[bb] = fmaf(rbase[bb*128 + h],     wv0, acc[bb]);
      acc[bb] = fmaf(rbase[bb*128 + h + 1], wv1, acc[bb]);
    }
  }
  #pragma unroll
  for (int bb = 0; bb < 16; ++bb)
    out[(long long)(bg*16 + bb)*VD + v] = acc[bb] + ob;
}

// ---------------------------------------------------------------------------
extern "C" void kernel_launch(void* const* d_in, const int* in_sizes, int n_in,
                              void* d_out, int out_size, void* d_ws, size_t ws_size,
                              hipStream_t stream)
{
  const int*   seq   = (const int*)d_in[0];
  const float* embed = (const float*)d_in[1];
  const float* w1    = (const float*)d_in[2];
  const float* b1    = (const float*)d_in[3];
  const float* w2    = (const float*)d_in[4];
  const float* b2    = (const float*)d_in[5];
  const float* ln_g  = (const float*)d_in[6];
  const float* ln_b  = (const float*)d_in[7];
  const float* kp_w  = (const float*)d_in[8];
  const float* rp_w  = (const float*)d_in[9];
  const float* rp_b  = (const float*)d_in[10];
  const float* out_w = (const float*)d_in[11];
  const float* out_b = (const float*)d_in[12];
  float* out = (float*)d_out;

  char* ws = (char*)d_ws;
  float* keys = (float*)ws;                               // 64 MiB
  float* Mg   = (float*)(ws + 67108864);                  // 4 MiB
  float* rr   = (float*)(ws + 67108864 + 4194304);        // 32 KiB

  hipLaunchKernelGGL(k_tokens, dim3(64*TBLK), dim3(512), 137216, stream,
                     seq, embed, w1, b1, w2, b2, ln_g, ln_b, kp_w, keys);
  hipLaunchKernelGGL(k_scan, dim3(64), dim3(768), 163328, stream, keys, Mg);
  hipLaunchKernelGGL(k_read, dim3(64), dim3(128), 0, stream, keys, Mg, rp_w, rp_b, rr);
  hipLaunchKernelGGL(k_out, dim3(500), dim3(256), 0, stream, rr, out_w, out_b, out);
}

// Round 15
// 756.766 us; speedup vs baseline: 1.2814x; 1.0153x over previous
//
#include <hip/hip_runtime.h>

#define HD 128
#define LD 2048
#define BD 64
#define VD 32000
#define NSTEP 2047   // L-1 scan steps, t = 0..2046

// f32 constants exactly matching the reference's f32-cast scalars
#define C_ALPHA  0.05f
#define C_THMIN  0.4f
#define C_THSPAN 1.1f
#define C_NEPS   1e-12f
#define C_LNEPS  1e-5f

// ---------------------------------------------------------------------------
// K1: fused embed-gather + MLP + LayerNorm + keys=hn@kp (round-14 exact).
// Only tokens >= 896 are live (first fire t=931).
// ---------------------------------------------------------------------------
#define HSP 132
#define W1P 68
#define W2P 132
#define ATP 68
#define TOK0 896
#define TBLK 9

extern "C" __global__ __launch_bounds__(512, 1)
void k_tokens(const int* __restrict__ seq, const float* __restrict__ embed,
              const float* __restrict__ w1, const float* __restrict__ b1,
              const float* __restrict__ w2, const float* __restrict__ b2,
              const float* __restrict__ lng, const float* __restrict__ lnb,
              const float* __restrict__ kp, float* __restrict__ keys)
{
  extern __shared__ float sm[];
  float* hs = sm;                 // [128][HSP]  h, later hn
  float* wt = sm + 128*HSP;       // [128][W1P] (w1 tile) or [64][W2P] (w2/kp)
  float* at = wt + 128*W1P;       // [128][ATP]  relu tile
  const int tid = threadIdx.x;
  const int bb  = blockIdx.x / TBLK;
  const int rel = blockIdx.x % TBLK;
  const long long tokBase = (long long)bb * LD + TOK0 + rel * 128;

  // ---- gather h = embed[seq]
  for (int u = tid; u < 128*32; u += 512) {
    const int tok = u >> 5, seg = u & 31;
    const int s = seq[tokBase + tok];
    *(float4*)(hs + tok*HSP + seg*4) =
        *(const float4*)(embed + (long long)s*HD + seg*4);
  }
  __syncthreads();

  const int tg = tid >> 5;   // token group 0..15: tok = tg + 16*r, r=0..7
  const int ig = tid & 31;   // column group 0..31

  float xacc[8][4] = {};     // x (MLP out): 8 tok x 4 i (i = ig*4+q)

  for (int jt = 0; jt < 4; ++jt) {
    // stage w1 tile [128 i][64 j]
    for (int u = tid; u < 128*16; u += 512) {
      const int i = u >> 4, q = u & 15;
      *(float4*)(wt + i*W1P + q*4) =
          *(const float4*)(w1 + (long long)i*256 + jt*64 + q*4);
    }
    __syncthreads();
    // a-tile = relu(h @ w1tile + b1): thread = 8 tok x 2 j  (j = ig*2+c)
    {
      float aa[8][2];
      float b1v[2];
      b1v[0] = b1[jt*64 + ig*2];
      b1v[1] = b1[jt*64 + ig*2 + 1];
      #pragma unroll
      for (int r = 0; r < 8; ++r) { aa[r][0] = b1v[0]; aa[r][1] = b1v[1]; }
      #pragma unroll 4
      for (int i4 = 0; i4 < 32; ++i4) {
        float2 wc[4];
        #pragma unroll
        for (int d = 0; d < 4; ++d)
          wc[d] = *(const float2*)(wt + (i4*4 + d)*W1P + ig*2);
        #pragma unroll
        for (int r = 0; r < 8; ++r) {
          float4 hv = *(const float4*)(hs + (tg + 16*r)*HSP + i4*4);
          aa[r][0] = fmaf(hv.x, wc[0].x, aa[r][0]);
          aa[r][0] = fmaf(hv.y, wc[1].x, aa[r][0]);
          aa[r][0] = fmaf(hv.z, wc[2].x, aa[r][0]);
          aa[r][0] = fmaf(hv.w, wc[3].x, aa[r][0]);
          aa[r][1] = fmaf(hv.x, wc[0].y, aa[r][1]);
          aa[r][1] = fmaf(hv.y, wc[1].y, aa[r][1]);
          aa[r][1] = fmaf(hv.z, wc[2].y, aa[r][1]);
          aa[r][1] = fmaf(hv.w, wc[3].y, aa[r][1]);
        }
      }
      #pragma unroll
      for (int r = 0; r < 8; ++r) {
        float2 o;
        o.x = fmaxf(aa[r][0], 0.0f);
        o.y = fmaxf(aa[r][1], 0.0f);
        *(float2*)(at + (tg + 16*r)*ATP + ig*2) = o;
      }
    }
    __syncthreads();
    // stage w2 tile [64 k][128 i]
    for (int u = tid; u < 64*32; u += 512) {
      const int k = u >> 5, q = u & 31;
      *(float4*)(wt + k*W2P + q*4) =
          *(const float4*)(w2 + (long long)(jt*64 + k)*128 + q*4);
    }
    __syncthreads();
    // x += a-tile @ w2tile: thread = 8 tok x 4 i
    #pragma unroll 2
    for (int k4 = 0; k4 < 16; ++k4) {
      float4 wr[4];
      #pragma unroll
      for (int d = 0; d < 4; ++d)
        wr[d] = *(const float4*)(wt + (k4*4 + d)*W2P + ig*4);
      #pragma unroll
      for (int r = 0; r < 8; ++r) {
        float4 av = *(const float4*)(at + (tg + 16*r)*ATP + k4*4);
        xacc[r][0] = fmaf(av.x, wr[0].x, xacc[r][0]);
        xacc[r][0] = fmaf(av.y, wr[1].x, xacc[r][0]);
        xacc[r][0] = fmaf(av.z, wr[2].x, xacc[r][0]);
        xacc[r][0] = fmaf(av.w, wr[3].x, xacc[r][0]);
        xacc[r][1] = fmaf(av.x, wr[0].y, xacc[r][1]);
        xacc[r][1] = fmaf(av.y, wr[1].y, xacc[r][1]);
        xacc[r][1] = fmaf(av.z, wr[2].y, xacc[r][1]);
        xacc[r][1] = fmaf(av.w, wr[3].y, xacc[r][1]);
        xacc[r][2] = fmaf(av.x, wr[0].z, xacc[r][2]);
        xacc[r][2] = fmaf(av.y, wr[1].z, xacc[r][2]);
        xacc[r][2] = fmaf(av.z, wr[2].z, xacc[r][2]);
        xacc[r][2] = fmaf(av.w, wr[3].z, xacc[r][2]);
        xacc[r][3] = fmaf(av.x, wr[0].w, xacc[r][3]);
        xacc[r][3] = fmaf(av.y, wr[1].w, xacc[r][3]);
        xacc[r][3] = fmaf(av.z, wr[2].w, xacc[r][3]);
        xacc[r][3] = fmaf(av.w, wr[3].w, xacc[r][3]);
      }
    }
    __syncthreads();
  }

  // ---- x = h + (x + b2); LayerNorm (32 lanes share a token); hn -> hs
  {
    float b2v[4], gv[4], bv[4];
    #pragma unroll
    for (int q = 0; q < 4; ++q) {
      b2v[q] = b2[ig*4 + q]; gv[q] = lng[ig*4 + q]; bv[q] = lnb[ig*4 + q];
    }
    #pragma unroll
    for (int r = 0; r < 8; ++r) {
      const int row = (tg + 16*r)*HSP + ig*4;
      float4 h0 = *(const float4*)(hs + row);
      float xr[4];
      xr[0] = h0.x + (xacc[r][0] + b2v[0]);
      xr[1] = h0.y + (xacc[r][1] + b2v[1]);
      xr[2] = h0.z + (xacc[r][2] + b2v[2]);
      xr[3] = h0.w + (xacc[r][3] + b2v[3]);
      float s = xr[0] + xr[1] + xr[2] + xr[3];
      s += __shfl_xor(s, 1, 32);  s += __shfl_xor(s, 2, 32);
      s += __shfl_xor(s, 4, 32);  s += __shfl_xor(s, 8, 32);
      s += __shfl_xor(s, 16, 32);
      const float mu = s * 0.0078125f;
      float vs = 0.0f;
      #pragma unroll
      for (int q = 0; q < 4; ++q) { float d = xr[q]-mu; vs = fmaf(d, d, vs); }
      vs += __shfl_xor(vs, 1, 32);  vs += __shfl_xor(vs, 2, 32);
      vs += __shfl_xor(vs, 4, 32);  vs += __shfl_xor(vs, 8, 32);
      vs += __shfl_xor(vs, 16, 32);
      const float rstd = 1.0f / sqrtf(vs * 0.0078125f + C_LNEPS);
      float4 o;
      o.x = (xr[0]-mu)*rstd*gv[0] + bv[0];
      o.y = (xr[1]-mu)*rstd*gv[1] + bv[1];
      o.z = (xr[2]-mu)*rstd*gv[2] + bv[2];
      o.w = (xr[3]-mu)*rstd*gv[3] + bv[3];
      *(float4*)(hs + row) = o;
    }
  }
  __syncthreads();

  // ---- keys = hn @ kp
  {
    float ky[8][4] = {};
    for (int kt = 0; kt < 2; ++kt) {
      for (int u = tid; u < 64*32; u += 512) {
        const int k = u >> 5, q = u & 31;
        *(float4*)(wt + k*W2P + q*4) =
            *(const float4*)(kp + (long long)(kt*64 + k)*128 + q*4);
      }
      __syncthreads();
      #pragma unroll 2
      for (int k4 = 0; k4 < 16; ++k4) {
        float4 wr[4];
        #pragma unroll
        for (int d = 0; d < 4; ++d)
          wr[d] = *(const float4*)(wt + (k4*4 + d)*W2P + ig*4);
        #pragma unroll
        for (int r = 0; r < 8; ++r) {
          float4 hv = *(const float4*)(hs + (tg + 16*r)*HSP + kt*64 + k4*4);
          ky[r][0] = fmaf(hv.x, wr[0].x, ky[r][0]);
          ky[r][0] = fmaf(hv.y, wr[1].x, ky[r][0]);
          ky[r][0] = fmaf(hv.z, wr[2].x, ky[r][0]);
          ky[r][0] = fmaf(hv.w, wr[3].x, ky[r][0]);
          ky[r][1] = fmaf(hv.x, wr[0].y, ky[r][1]);
          ky[r][1] = fmaf(hv.y, wr[1].y, ky[r][1]);
          ky[r][1] = fmaf(hv.z, wr[2].y, ky[r][1]);
          ky[r][1] = fmaf(hv.w, wr[3].y, ky[r][1]);
          ky[r][2] = fmaf(hv.x, wr[0].z, ky[r][2]);
          ky[r][2] = fmaf(hv.y, wr[1].z, ky[r][2]);
          ky[r][2] = fmaf(hv.z, wr[2].z, ky[r][2]);
          ky[r][2] = fmaf(hv.w, wr[3].z, ky[r][2]);
          ky[r][3] = fmaf(hv.x, wr[0].w, ky[r][3]);
          ky[r][3] = fmaf(hv.y, wr[1].w, ky[r][3]);
          ky[r][3] = fmaf(hv.z, wr[2].w, ky[r][3]);
          ky[r][3] = fmaf(hv.w, wr[3].w, ky[r][3]);
        }
      }
      __syncthreads();
    }
    #pragma unroll
    for (int r = 0; r < 8; ++r) {
      const long long g = tokBase + tg + 16*r;
      float4 o;
      o.x = ky[r][0]; o.y = ky[r][1]; o.z = ky[r][2]; o.w = ky[r][3];
      *(float4*)(keys + g*HD + ig*4) = o;
    }
  }
}

// ---------------------------------------------------------------------------
// K3: the scan — round-11 structure + (a) s_setprio(1) around wave0's
// serial recurrence (role-diverse waves: the T5 regime where priority
// boost pays), (b) fused k_read epilogue: M is already in LDS, so compute
// read = M@q and rr = read@rp_w + rp_b in-block; the 4 MB Mg write and the
// separate k_read kernel are eliminated.
// 64 blocks x 768 threads (12 waves, 3/SIMD). 2 barriers/chunk.
// Chunks < 29 provably dead (first fire t=931). Dynamic LDS = 163328 B.
// ---------------------------------------------------------------------------
#define C0 29
#define MSP 132   // Msh pitch
#define GPW 36    // G/Gx pitch
#define NT 768

#define INVB(buf,tok) Gxl[(tok)*GPW + 32 + (buf)]
#define TN2B(buf,tok) Gxl[(tok)*GPW + 34 + (buf)]

__device__ __forceinline__ float dpp_add_b1(float x){int y=__builtin_amdgcn_update_dpp(0,__float_as_int(x),0xB1,0xf,0xf,true);return x+__int_as_float(y);}
__device__ __forceinline__ float dpp_add_4e(float x){int y=__builtin_amdgcn_update_dpp(0,__float_as_int(x),0x4E,0xf,0xf,true);return x+__int_as_float(y);}
__device__ __forceinline__ float dpp_add_hm(float x){int y=__builtin_amdgcn_update_dpp(0,__float_as_int(x),0x141,0xf,0xf,true);return x+__int_as_float(y);}
__device__ __forceinline__ float dpp_add_mr(float x){int y=__builtin_amdgcn_update_dpp(0,__float_as_int(x),0x140,0xf,0xf,true);return x+__int_as_float(y);}
__device__ __forceinline__ float dpp_add_b15(float x){int y=__builtin_amdgcn_update_dpp(0,__float_as_int(x),0x142,0xf,0xf,true);return x+__int_as_float(y);}
__device__ __forceinline__ float dpp_add_b31(float x){int y=__builtin_amdgcn_update_dpp(0,__float_as_int(x),0x143,0xf,0xf,true);return x+__int_as_float(y);}

// G / Gx half-tile: 32 s-rows x 16 t-cols, one wave. Row pitch 128 with
// per-lane column rotation (2-way banks). Stride-8 row blocking.
__device__ __forceinline__ void gram_half(const float* bufS, const float* bufT,
                                          float* dst, int half, int lane)
{
  const int sq = lane & 7, tq = lane >> 3;
  float ga[4][2] = {};
  for (int j4 = 0; j4 < 32; ++j4) {
    const int col = ((j4 + lane) & 31) * 4;
    float4 sv[4], tv[2];
    #pragma unroll
    for (int r = 0; r < 4; ++r)
      sv[r] = *(const float4*)(bufS + (sq + 8*r)*128 + col);
    #pragma unroll
    for (int q = 0; q < 2; ++q)
      tv[q] = *(const float4*)(bufT + (half*16 + tq*2 + q)*128 + col);
    #pragma unroll
    for (int r = 0; r < 4; ++r)
      #pragma unroll
      for (int q = 0; q < 2; ++q) {
        ga[r][q] = fmaf(sv[r].x, tv[q].x, ga[r][q]);
        ga[r][q] = fmaf(sv[r].y, tv[q].y, ga[r][q]);
        ga[r][q] = fmaf(sv[r].z, tv[q].z, ga[r][q]);
        ga[r][q] = fmaf(sv[r].w, tv[q].w, ga[r][q]);
      }
  }
  #pragma unroll
  for (int r = 0; r < 4; ++r)
    #pragma unroll
    for (int q = 0; q < 2; ++q)
      dst[(sq + 8*r)*GPW + half*16 + tq*2 + q] = ga[r][q];
}

extern "C" __global__ __launch_bounds__(768)
void k_scan(const float* __restrict__ keys,
            const float* __restrict__ rpw, const float* __restrict__ rpb,
            float* __restrict__ rr)
{
  extern __shared__ float sm[];
  float* Msh  = sm;                    // [128][132]           16896
  float* kbuf = Msh + 128*MSP;         // [3][32][128]         12288
  float* PW   = kbuf + 3*4096;         // [2][32][128]          8192
  float* Gb   = PW + 2*4096;           // [2][32][36]           2304
  float* Gxl  = Gb + 2*32*GPW;         // [32][36] (+inv/tn2)   1152
  // total 40832 floats = 163328 B

  const int tid  = threadIdx.x;
  const int lane = tid & 63;
  const int w    = tid >> 6;
  const int b    = blockIdx.x;
  const float* kb = keys + (long long)b * LD * HD;

  // ---------------- prologue ----------------
  for (int u = tid; u < 128*MSP; u += NT) Msh[u] = 0.0f;
  for (int u = tid; u < 4096; u += NT) PW[(C0&1)*4096 + u] = 0.0f;  // P(C0)=0
  {
    const int b30 = C0 % 3;   // = 2
    for (int u = tid; u < 1024; u += NT)
      *(float4*)(kbuf + b30*4096 + u*4) =
          *(const float4*)(kb + (long long)(C0*32)*HD + u*4);
  }
  __syncthreads();
  {
    const float* kc = kbuf + (C0%3)*4096;
    for (int u = tid; u < 1024; u += NT) {
      const int s = u >> 5, t = u & 31;
      float a = 0.0f;
      for (int j4 = 0; j4 < 32; ++j4) {
        const int col = ((j4 + tid) & 31) * 4;
        float4 sv = *(const float4*)(kc + s*128 + col);
        float4 tv = *(const float4*)(kc + t*128 + col);
        a = fmaf(sv.x,tv.x,a); a = fmaf(sv.y,tv.y,a);
        a = fmaf(sv.z,tv.z,a); a = fmaf(sv.w,tv.w,a);
      }
      Gb[(C0&1)*32*GPW + s*GPW + t] = a;
    }
  }
  if (tid < 256) {
    const int tok = tid >> 3, pp = tid & 7;
    const float* kc = kbuf + (C0%3)*4096;
    float ss = 0.0f;
    #pragma unroll
    for (int q = 0; q < 4; ++q) {
      float4 v = *(const float4*)(kc + tok*128 + pp*16 + q*4);
      ss = fmaf(v.x,v.x,ss); ss = fmaf(v.y,v.y,ss);
      ss = fmaf(v.z,v.z,ss); ss = fmaf(v.w,v.w,ss);
    }
    ss += __shfl_xor(ss,1,8); ss += __shfl_xor(ss,2,8); ss += __shfl_xor(ss,4,8);
    if (pp == 0) {
      const float n = sqrtf(ss);
      INVB(C0&1, tok) = 1.0f / fmaxf(n, C_NEPS);
      const float th = C_THMIN + C_THSPAN * (1.0f - (float)(C0*32 + tok) / 2047.0f);
      const float tn = th * n;
      TN2B(C0&1, tok) = tn * tn;
    }
  }
  __syncthreads();

  // ---------------- main loop ----------------
  for (int c = C0; c <= 64; ++c) {
    const int cur = c & 1, nxt = cur ^ 1;
    const int b3c = c % 3;            // kf(c)
    const int b3n = (c + 1) % 3;      // kf(c+1) dest
    const int b3p = (c + 2) % 3;      // == (c-1)%3, kf(c-1)
    const int t0 = c * 32;

    // ===== phase A =====
    if (w < 8) {
      // U(c-1): M += alpha * W2_{c-1}^T kf_{c-1}   (8i x 4j register tiles)
      if (c > C0) {
        const int it = tid >> 5;       // 0..15
        const int jt = tid & 31;       // 0..31
        const int i0 = it*8, j0 = jt*4;
        const float* Wp  = PW + nxt*4096;
        const float* kfp = kbuf + b3p*4096;
        float acc[8][4] = {};
        for (int s = 0; s < 32; ++s) {
          const float4 wa = *(const float4*)(Wp + s*128 + i0);
          const float4 wb = *(const float4*)(Wp + s*128 + i0 + 4);
          const float4 k4 = *(const float4*)(kfp + s*128 + j0);
          float wv[8] = {wa.x,wa.y,wa.z,wa.w,wb.x,wb.y,wb.z,wb.w};
          float kv[4] = {k4.x,k4.y,k4.z,k4.w};
          #pragma unroll
          for (int a = 0; a < 8; ++a)
            #pragma unroll
            for (int q = 0; q < 4; ++q)
              acc[a][q] = fmaf(wv[a], kv[q], acc[a][q]);
        }
        #pragma unroll
        for (int a = 0; a < 8; ++a) {
          float* mp = Msh + (i0 + a)*MSP + j0;
          float4 m = *(float4*)mp;
          m.x = fmaf(C_ALPHA, acc[a][0], m.x);
          m.y = fmaf(C_ALPHA, acc[a][1], m.y);
          m.z = fmaf(C_ALPHA, acc[a][2], m.z);
          m.w = fmaf(C_ALPHA, acc[a][3], m.w);
          *(float4*)mp = m;
        }
      }
    } else {
      // waves 8-11: stage kf(c+1) + fixup P(c) (4t x 4i register tiles)
      const int t2id = tid - 512;      // 0..255
      float4 kvl[4];
      if (c < 63) {
        #pragma unroll
        for (int q = 0; q < 4; ++q)
          kvl[q] = *(const float4*)(kb + (long long)(t0 + 32)*HD + (t2id + 256*q)*4);
      }
      if (c > C0 && c <= 63) {
        const int tt = t2id >> 5;            // 0..7
        const int i0 = (t2id & 31) * 4;
        const int tb4 = tt*4;
        const float* Wp = PW + nxt*4096;
        float fac[4][4] = {};
        for (int s = 0; s < 32; ++s) {
          const float4 gx = *(const float4*)(Gxl + s*GPW + tb4);
          const float4 wp = *(const float4*)(Wp + s*128 + i0);
          float gv[4] = {gx.x,gx.y,gx.z,gx.w};
          float pv[4] = {wp.x,wp.y,wp.z,wp.w};
          #pragma unroll
          for (int a = 0; a < 4; ++a)
            #pragma unroll
            for (int q = 0; q < 4; ++q)
              fac[a][q] = fmaf(gv[a], pv[q], fac[a][q]);
        }
        float* Pp = PW + cur*4096;
        #pragma unroll
        for (int a = 0; a < 4; ++a) {
          float* pp = Pp + (tb4 + a)*128 + i0;
          float4 p = *(float4*)pp;
          p.x = fmaf(C_ALPHA, fac[a][0], p.x);
          p.y = fmaf(C_ALPHA, fac[a][1], p.y);
          p.z = fmaf(C_ALPHA, fac[a][2], p.z);
          p.w = fmaf(C_ALPHA, fac[a][3], p.w);
          *(float4*)pp = p;
        }
      }
      if (c < 63) {
        #pragma unroll
        for (int q = 0; q < 4; ++q)
          *(float4*)(kbuf + b3n*4096 + (t2id + 256*q)*4) = kvl[q];
      }
    }
    __syncthreads();
    if (c == 64) break;

    // ===== phase B (role waves, SIMD-balanced) =====
    if (w == 0) {
      // in-wave recurrence, acc[16] x 2 halves + register bridge (no spill)
      __builtin_amdgcn_s_setprio(1);
      float* Pc = PW + cur*4096;
      const float* kfc = kbuf + b3c*4096;
      const float* Gc  = Gb + cur*32*GPW;
      const int l2 = lane*2;
      float2 acc[16];
      #pragma unroll
      for (int u = 0; u < 16; ++u) { acc[u].x = 0.0f; acc[u].y = 0.0f; }
      // ---- half 0: t = 0..15
      #pragma unroll
      for (int t = 0; t < 16; ++t) {
        const float2 p2 = *(const float2*)(Pc + t*128 + l2);
        const float2 k2 = *(const float2*)(kfc + t*128 + l2);
        const float it = INVB(cur, t);
        const float vx = it * fmaf(C_ALPHA, acc[t].x, p2.x);
        const float vy = it * fmaf(C_ALPHA, acc[t].y, p2.y);
        const float ex = k2.x - vx;
        const float ey = k2.y - vy;
        float e2 = fmaf(ex, ex, ey*ey);
        e2 = dpp_add_b1(e2); e2 = dpp_add_4e(e2);
        e2 = dpp_add_hm(e2); e2 = dpp_add_mr(e2);
        e2 = dpp_add_b15(e2); e2 = dpp_add_b31(e2);
        const float en2 = __int_as_float(__builtin_amdgcn_readlane(__float_as_int(e2), 63));
        const bool fire = (en2 >= TN2B(cur, t));
        const float wx = fire ? ex * it : 0.0f;
        const float wy = fire ? ey * it : 0.0f;
        float2 w2v; w2v.x = wx; w2v.y = wy;
        *(float2*)(Pc + t*128 + l2) = w2v;
        const float* gr = Gc + t*GPW;
        #pragma unroll
        for (int u4 = (t+1) & ~3; u4 < 16; u4 += 4) {
          const float4 g = *(const float4*)(gr + u4);
          acc[u4+0].x = fmaf(wx, g.x, acc[u4+0].x); acc[u4+0].y = fmaf(wy, g.x, acc[u4+0].y);
          acc[u4+1].x = fmaf(wx, g.y, acc[u4+1].x); acc[u4+1].y = fmaf(wy, g.y, acc[u4+1].y);
          acc[u4+2].x = fmaf(wx, g.z, acc[u4+2].x); acc[u4+2].y = fmaf(wy, g.z, acc[u4+2].y);
          acc[u4+3].x = fmaf(wx, g.w, acc[u4+3].x); acc[u4+3].y = fmaf(wy, g.w, acc[u4+3].y);
        }
      }
      // ---- bridge: acc[u] = sum_{s<16} w2[s] * G[s][16+u]  (G symmetric)
      #pragma unroll
      for (int u = 0; u < 16; ++u) { acc[u].x = 0.0f; acc[u].y = 0.0f; }
      #pragma unroll
      for (int s = 0; s < 16; ++s) {
        const float2 ws = *(const float2*)(Pc + s*128 + l2);
        const float* gs = Gc + s*GPW + 16;
        #pragma unroll
        for (int u4 = 0; u4 < 16; u4 += 4) {
          const float4 g = *(const float4*)(gs + u4);
          acc[u4+0].x = fmaf(ws.x, g.x, acc[u4+0].x); acc[u4+0].y = fmaf(ws.y, g.x, acc[u4+0].y);
          acc[u4+1].x = fmaf(ws.x, g.y, acc[u4+1].x); acc[u4+1].y = fmaf(ws.y, g.y, acc[u4+1].y);
          acc[u4+2].x = fmaf(ws.x, g.z, acc[u4+2].x); acc[u4+2].y = fmaf(ws.y, g.z, acc[u4+2].y);
          acc[u4+3].x = fmaf(ws.x, g.w, acc[u4+3].x); acc[u4+3].y = fmaf(ws.y, g.w, acc[u4+3].y);
        }
      }
      // ---- half 1: t = 16..31
      #pragma unroll
      for (int t = 16; t < 32; ++t) {
        const int tt = t - 16;
        const float2 p2 = *(const float2*)(Pc + t*128 + l2);
        const float2 k2 = *(const float2*)(kfc + t*128 + l2);
        const float it = INVB(cur, t);
        const float vx = it * fmaf(C_ALPHA, acc[tt].x, p2.x);
        const float vy = it * fmaf(C_ALPHA, acc[tt].y, p2.y);
        const float ex = k2.x - vx;
        const float ey = k2.y - vy;
        float e2 = fmaf(ex, ex, ey*ey);
        e2 = dpp_add_b1(e2); e2 = dpp_add_4e(e2);
        e2 = dpp_add_hm(e2); e2 = dpp_add_mr(e2);
        e2 = dpp_add_b15(e2); e2 = dpp_add_b31(e2);
        const float en2 = __int_as_float(__builtin_amdgcn_readlane(__float_as_int(e2), 63));
        const bool fire = (en2 >= TN2B(cur, t)) && (t0 + t < NSTEP);
        const float wx = fire ? ex * it : 0.0f;
        const float wy = fire ? ey * it : 0.0f;
        float2 w2v; w2v.x = wx; w2v.y = wy;
        *(float2*)(Pc + t*128 + l2) = w2v;
        const float* gr = Gc + t*GPW + 16;
        #pragma unroll
        for (int u4 = (tt+1) & ~3; u4 < 16; u4 += 4) {
          const float4 g = *(const float4*)(gr + u4);
          acc[u4+0].x = fmaf(wx, g.x, acc[u4+0].x); acc[u4+0].y = fmaf(wy, g.x, acc[u4+0].y);
          acc[u4+1].x = fmaf(wx, g.y, acc[u4+1].x); acc[u4+1].y = fmaf(wy, g.y, acc[u4+1].y);
          acc[u4+2].x = fmaf(wx, g.z, acc[u4+2].x); acc[u4+2].y = fmaf(wy, g.z, acc[u4+2].y);
          acc[u4+3].x = fmaf(wx, g.w, acc[u4+3].x); acc[u4+3].y = fmaf(wy, g.w, acc[u4+3].y);
        }
      }
      __builtin_amdgcn_s_setprio(0);
    } else if (c < 63) {
      // SIMD-balanced role map:
      //  P_pre shares: w4->0, w8->1 (S0); w1,w5,w9 -> 2,3,4 (S1);
      //                w2,w6,w10 -> 5,6,7 (S2)
      //  S3: w3 = G h0, w7 = G h1, w11 = Gx h0 + h1
      //  norms: on w4 after its P_pre share.
      int p;
      switch (w) {
        case 4:  p = 0; break;  case 8:  p = 1; break;
        case 1:  p = 2; break;  case 5:  p = 3; break;  case 9:  p = 4; break;
        case 2:  p = 5; break;  case 6:  p = 6; break;  case 10: p = 7; break;
        default: p = -1;
      }
      if (p >= 0) {
        // P_pre(c+1) share: t' in [4p,4p+4), all 128 i
        const float* kfn = kbuf + b3n*4096;
        const int tb4 = p*4;
        const int ib = lane & 31, ih = lane >> 5;
        float pa[4][2] = {};
        for (int j4 = 0; j4 < 32; ++j4) {
          float4 kv[4], mv[2];
          #pragma unroll
          for (int ss = 0; ss < 4; ++ss)
            kv[ss] = *(const float4*)(kfn + (tb4+ss)*128 + j4*4);
          #pragma unroll
          for (int r = 0; r < 2; ++r)
            mv[r] = *(const float4*)(Msh + (ib + 32*(ih + 2*r))*MSP + j4*4);
          #pragma unroll
          for (int ss = 0; ss < 4; ++ss)
            #pragma unroll
            for (int r = 0; r < 2; ++r) {
              pa[ss][r] = fmaf(kv[ss].x, mv[r].x, pa[ss][r]);
              pa[ss][r] = fmaf(kv[ss].y, mv[r].y, pa[ss][r]);
              pa[ss][r] = fmaf(kv[ss].z, mv[r].z, pa[ss][r]);
              pa[ss][r] = fmaf(kv[ss].w, mv[r].w, pa[ss][r]);
            }
        }
        float* Pp = PW + nxt*4096;
        #pragma unroll
        for (int ss = 0; ss < 4; ++ss)
          #pragma unroll
          for (int r = 0; r < 2; ++r)
            Pp[(tb4+ss)*128 + ib + 32*(ih + 2*r)] = pa[ss][r];
        if (w == 4) {
          // norms(c+1) (2 lanes per token)
          const float* kn = kbuf + b3n*4096;
          const int tok = lane >> 1, hh = lane & 1;
          float ss2 = 0.0f;
          #pragma unroll
          for (int q = 0; q < 16; ++q) {
            const int cq = (q + lane) & 15;
            float4 v = *(const float4*)(kn + tok*128 + hh*64 + cq*4);
            ss2 = fmaf(v.x,v.x,ss2); ss2 = fmaf(v.y,v.y,ss2);
            ss2 = fmaf(v.z,v.z,ss2); ss2 = fmaf(v.w,v.w,ss2);
          }
          ss2 += __shfl_xor(ss2, 1);
          if (hh == 0) {
            const float n = sqrtf(ss2);
            INVB(nxt, tok) = 1.0f / fmaxf(n, C_NEPS);
            const float th = C_THMIN + C_THSPAN * (1.0f - (float)(t0 + 32 + tok) / 2047.0f);
            const float tn = th * n;
            TN2B(nxt, tok) = tn * tn;
          }
        }
      } else if (w == 3) {
        gram_half(kbuf + b3n*4096, kbuf + b3n*4096, Gb + nxt*32*GPW, 0, lane);
      } else if (w == 7) {
        gram_half(kbuf + b3n*4096, kbuf + b3n*4096, Gb + nxt*32*GPW, 1, lane);
      } else {
        // w == 11: Gx(c,c+1) both halves
        gram_half(kbuf + b3c*4096, kbuf + b3n*4096, Gxl, 0, lane);
        gram_half(kbuf + b3c*4096, kbuf + b3n*4096, Gxl, 1, lane);
      }
    }
    __syncthreads();
  }

  // ---------------- fused k_read epilogue ----------------
  // read = M @ q ; rr[b] = read @ rp_w + rp_b.  M is in Msh; q = keys row 2047.
  {
    float* qv = PW;          // reuse [128]
    float* rd = PW + 128;    // reuse [128]
    if (tid < 32)
      *(float4*)(qv + tid*4) =
          *(const float4*)(kb + (long long)(LD-1)*HD + tid*4);
    __syncthreads();
    if (tid < 512) {
      const int i = tid >> 2, p = tid & 3;   // 4 lanes per row
      const float* mr = Msh + i*MSP + p*32;
      const float* qp = qv + p*32;
      float a0 = 0.0f, a1 = 0.0f;
      #pragma unroll
      for (int q4 = 0; q4 < 8; q4 += 2) {
        const float4 m0 = *(const float4*)(mr + q4*4);
        const float4 m1 = *(const float4*)(mr + q4*4 + 4);
        a0 = fmaf(m0.x, qp[q4*4+0], a0); a0 = fmaf(m0.y, qp[q4*4+1], a0);
        a0 = fmaf(m0.z, qp[q4*4+2], a0); a0 = fmaf(m0.w, qp[q4*4+3], a0);
        a1 = fmaf(m1.x, qp[q4*4+4], a1); a1 = fmaf(m1.y, qp[q4*4+5], a1);
        a1 = fmaf(m1.z, qp[q4*4+6], a1); a1 = fmaf(m1.w, qp[q4*4+7], a1);
      }
      float acc = a0 + a1;
      acc += __shfl_xor(acc, 1);
      acc += __shfl_xor(acc, 2);
      if (p == 0) rd[i] = acc;
    }
    __syncthreads();
    if (tid < 128) {
      float s0 = rpb[tid], s1 = 0.0f, s2 = 0.0f, s3 = 0.0f;
      for (int k = 0; k < 128; k += 4) {
        s0 = fmaf(rd[k+0], rpw[(k+0)*128 + tid], s0);
        s1 = fmaf(rd[k+1], rpw[(k+1)*128 + tid], s1);
        s2 = fmaf(rd[k+2], rpw[(k+2)*128 + tid], s2);
        s3 = fmaf(rd[k+3], rpw[(k+3)*128 + tid], s3);
      }
      rr[b*128 + tid] = (s0 + s1) + (s2 + s3);
    }
  }
}

// ---------------------------------------------------------------------------
// K4b: out[b][v] = rr[b] . out_w[:,v] + out_b[v]  (round-14 exact)
// 500 blocks x 256 threads; v-tile 64, 4 batch-groups of 16; h-unroll x2.
// ---------------------------------------------------------------------------
extern "C" __global__ __launch_bounds__(256, 1)
void k_out(const float* __restrict__ rr, const float* __restrict__ outw,
           const float* __restrict__ outb, float* __restrict__ out)
{
  __shared__ float rl[64*128];
  const int tid = threadIdx.x;
  for (int u = tid; u < 8192; u += 256) rl[u] = rr[u];
  __syncthreads();
  const int v  = blockIdx.x*64 + (tid & 63);
  const int bg = tid >> 6;   // 0..3 -> batches bg*16..+15
  const float ob = outb[v];
  const float* rbase = rl + bg*16*128;
  float acc[16];
  #pragma unroll
  for (int bb = 0; bb < 16; ++bb) acc[bb] = 0.0f;
  for (int h = 0; h < 128; h += 2) {
    const float wv0 = outw[(long long)h*VD + v];
    const float wv1 = outw[(long long)(h+1)*VD + v];
    #pragma unroll
    for (int bb = 0; bb < 16; ++bb) {
      acc[bb] = fmaf(rbase[bb*128 + h],     wv0, acc[bb]);
      acc[bb] = fmaf(rbase[bb*128 + h + 1], wv1, acc[bb]);
    }
  }
  #pragma unroll
  for (int bb = 0; bb < 16; ++bb)
    out[(long long)(bg*16 + bb)*VD + v] = acc[bb] + ob;
}

// ---------------------------------------------------------------------------
extern "C" void kernel_launch(void* const* d_in, const int* in_sizes, int n_in,
                              void* d_out, int out_size, void* d_ws, size_t ws_size,
                              hipStream_t stream)
{
  const int*   seq   = (const int*)d_in[0];
  const float* embed = (const float*)d_in[1];
  const float* w1    = (const float*)d_in[2];
  const float* b1    = (const float*)d_in[3];
  const float* w2    = (const float*)d_in[4];
  const float* b2    = (const float*)d_in[5];
  const float* ln_g  = (const float*)d_in[6];
  const float* ln_b  = (const float*)d_in[7];
  const float* kp_w  = (const float*)d_in[8];
  const float* rp_w  = (const float*)d_in[9];
  const float* rp_b  = (const float*)d_in[10];
  const float* out_w = (const float*)d_in[11];
  const float* out_b = (const float*)d_in[12];
  float* out = (float*)d_out;

  char* ws = (char*)d_ws;
  float* keys = (float*)ws;                               // 64 MiB
  float* rr   = (float*)(ws + 67108864 + 4194304);        // 32 KiB

  hipLaunchKernelGGL(k_tokens, dim3(64*TBLK), dim3(512), 137216, stream,
                     seq, embed, w1, b1, w2, b2, ln_g, ln_b, kp_w, keys);
  hipLaunchKernelGGL(k_scan, dim3(64), dim3(768), 163328, stream,
                     keys, rp_w, rp_b, rr);
  hipLaunchKernelGGL(k_out, dim3(500), dim3(256), 0, stream, rr, out_w, out_b, out);
}

// Round 16
// 636.541 us; speedup vs baseline: 1.5234x; 1.1889x over previous
//
#include <hip/hip_runtime.h>

#define HD 128
#define LD 2048
#define BD 64
#define VD 32000
#define NSTEP 2047   // L-1 scan steps, t = 0..2046

// f32 constants exactly matching the reference's f32-cast scalars
#define C_ALPHA  0.05f
#define C_THMIN  0.4f
#define C_THSPAN 1.1f
#define C_NEPS   1e-12f
#define C_LNEPS  1e-5f

#define HSP 132
#define W1P 68
#define W2P 132
#define ATP 68
#define TOK0 896

#define C0 29
#define MSP 132   // Msh pitch
#define GPW 36    // G/Gx pitch
#define NT 768

#define INVB(buf,tok) Gxl[(tok)*GPW + 32 + (buf)]
#define TN2B(buf,tok) Gxl[(tok)*GPW + 34 + (buf)]

__device__ __forceinline__ float dpp_add_b1(float x){int y=__builtin_amdgcn_update_dpp(0,__float_as_int(x),0xB1,0xf,0xf,true);return x+__int_as_float(y);}
__device__ __forceinline__ float dpp_add_4e(float x){int y=__builtin_amdgcn_update_dpp(0,__float_as_int(x),0x4E,0xf,0xf,true);return x+__int_as_float(y);}
__device__ __forceinline__ float dpp_add_hm(float x){int y=__builtin_amdgcn_update_dpp(0,__float_as_int(x),0x141,0xf,0xf,true);return x+__int_as_float(y);}
__device__ __forceinline__ float dpp_add_mr(float x){int y=__builtin_amdgcn_update_dpp(0,__float_as_int(x),0x140,0xf,0xf,true);return x+__int_as_float(y);}
__device__ __forceinline__ float dpp_add_b15(float x){int y=__builtin_amdgcn_update_dpp(0,__float_as_int(x),0x142,0xf,0xf,true);return x+__int_as_float(y);}
__device__ __forceinline__ float dpp_add_b31(float x){int y=__builtin_amdgcn_update_dpp(0,__float_as_int(x),0x143,0xf,0xf,true);return x+__int_as_float(y);}

__device__ __forceinline__ void wait_flag(int* flags, int idx) {
  while (__hip_atomic_load(&flags[idx], __ATOMIC_ACQUIRE,
                           __HIP_MEMORY_SCOPE_AGENT) == 0)
    __builtin_amdgcn_s_sleep(16);
}

// G / Gx half-tile: 32 s-rows x 16 t-cols, one wave. Row pitch 128 with
// per-lane column rotation (2-way banks). Stride-8 row blocking.
__device__ __forceinline__ void gram_half(const float* bufS, const float* bufT,
                                          float* dst, int half, int lane)
{
  const int sq = lane & 7, tq = lane >> 3;
  float ga[4][2] = {};
  for (int j4 = 0; j4 < 32; ++j4) {
    const int col = ((j4 + lane) & 31) * 4;
    float4 sv[4], tv[2];
    #pragma unroll
    for (int r = 0; r < 4; ++r)
      sv[r] = *(const float4*)(bufS + (sq + 8*r)*128 + col);
    #pragma unroll
    for (int q = 0; q < 2; ++q)
      tv[q] = *(const float4*)(bufT + (half*16 + tq*2 + q)*128 + col);
    #pragma unroll
    for (int r = 0; r < 4; ++r)
      #pragma unroll
      for (int q = 0; q < 2; ++q) {
        ga[r][q] = fmaf(sv[r].x, tv[q].x, ga[r][q]);
        ga[r][q] = fmaf(sv[r].y, tv[q].y, ga[r][q]);
        ga[r][q] = fmaf(sv[r].z, tv[q].z, ga[r][q]);
        ga[r][q] = fmaf(sv[r].w, tv[q].w, ga[r][q]);
      }
  }
  #pragma unroll
  for (int r = 0; r < 4; ++r)
    #pragma unroll
    for (int q = 0; q < 2; ++q)
      dst[(sq + 8*r)*GPW + half*16 + tq*2 + q] = ga[r][q];
}

// ---------------------------------------------------------------------------
// Producer tile: 64 tokens (batch bb, rows TOK0+rel*64 ..+63). Same per-token
// math/order as the round-14 k_tokens (r-loop shortened 8->4). tid<512 active;
// threads 512-767 participate in barriers only.
// LDS prefix use: hs[64][132] | wt[128][68]/[64][132] | at[64][68]  (~86 KB)
// ---------------------------------------------------------------------------
__device__ void produce_tile(int bb, int rel,
                             const int* __restrict__ seq, const float* __restrict__ embed,
                             const float* __restrict__ w1, const float* __restrict__ b1,
                             const float* __restrict__ w2, const float* __restrict__ b2,
                             const float* __restrict__ lng, const float* __restrict__ lnb,
                             const float* __restrict__ kp, float* __restrict__ keys,
                             float* sm, int tid)
{
  float* hs = sm;                 // [64][HSP]
  float* wt = sm + 64*HSP;        // [128][W1P] or [64][W2P]
  float* at = wt + 128*W1P;       // [64][ATP]
  const long long tokBase = (long long)bb * LD + TOK0 + rel * 64;

  if (tid < 512)
    for (int u = tid; u < 64*32; u += 512) {
      const int tok = u >> 5, seg = u & 31;
      const int s = seq[tokBase + tok];
      *(float4*)(hs + tok*HSP + seg*4) =
          *(const float4*)(embed + (long long)s*HD + seg*4);
    }
  __syncthreads();

  const int tg = (tid >> 5) & 15;
  const int ig = tid & 31;
  float xacc[4][4] = {};

  for (int jt = 0; jt < 4; ++jt) {
    if (tid < 512)
      for (int u = tid; u < 128*16; u += 512) {
        const int i = u >> 4, q = u & 15;
        *(float4*)(wt + i*W1P + q*4) =
            *(const float4*)(w1 + (long long)i*256 + jt*64 + q*4);
      }
    __syncthreads();
    if (tid < 512) {
      float aa[4][2];
      float b1v[2];
      b1v[0] = b1[jt*64 + ig*2];
      b1v[1] = b1[jt*64 + ig*2 + 1];
      #pragma unroll
      for (int r = 0; r < 4; ++r) { aa[r][0] = b1v[0]; aa[r][1] = b1v[1]; }
      #pragma unroll 4
      for (int i4 = 0; i4 < 32; ++i4) {
        float2 wc[4];
        #pragma unroll
        for (int d = 0; d < 4; ++d)
          wc[d] = *(const float2*)(wt + (i4*4 + d)*W1P + ig*2);
        #pragma unroll
        for (int r = 0; r < 4; ++r) {
          float4 hv = *(const float4*)(hs + (tg + 16*r)*HSP + i4*4);
          aa[r][0] = fmaf(hv.x, wc[0].x, aa[r][0]);
          aa[r][0] = fmaf(hv.y, wc[1].x, aa[r][0]);
          aa[r][0] = fmaf(hv.z, wc[2].x, aa[r][0]);
          aa[r][0] = fmaf(hv.w, wc[3].x, aa[r][0]);
          aa[r][1] = fmaf(hv.x, wc[0].y, aa[r][1]);
          aa[r][1] = fmaf(hv.y, wc[1].y, aa[r][1]);
          aa[r][1] = fmaf(hv.z, wc[2].y, aa[r][1]);
          aa[r][1] = fmaf(hv.w, wc[3].y, aa[r][1]);
        }
      }
      #pragma unroll
      for (int r = 0; r < 4; ++r) {
        float2 o;
        o.x = fmaxf(aa[r][0], 0.0f);
        o.y = fmaxf(aa[r][1], 0.0f);
        *(float2*)(at + (tg + 16*r)*ATP + ig*2) = o;
      }
    }
    __syncthreads();
    if (tid < 512)
      for (int u = tid; u < 64*32; u += 512) {
        const int k = u >> 5, q = u & 31;
        *(float4*)(wt + k*W2P + q*4) =
            *(const float4*)(w2 + (long long)(jt*64 + k)*128 + q*4);
      }
    __syncthreads();
    if (tid < 512) {
      #pragma unroll 2
      for (int k4 = 0; k4 < 16; ++k4) {
        float4 wr[4];
        #pragma unroll
        for (int d = 0; d < 4; ++d)
          wr[d] = *(const float4*)(wt + (k4*4 + d)*W2P + ig*4);
        #pragma unroll
        for (int r = 0; r < 4; ++r) {
          float4 av = *(const float4*)(at + (tg + 16*r)*ATP + k4*4);
          xacc[r][0] = fmaf(av.x, wr[0].x, xacc[r][0]);
          xacc[r][0] = fmaf(av.y, wr[1].x, xacc[r][0]);
          xacc[r][0] = fmaf(av.z, wr[2].x, xacc[r][0]);
          xacc[r][0] = fmaf(av.w, wr[3].x, xacc[r][0]);
          xacc[r][1] = fmaf(av.x, wr[0].y, xacc[r][1]);
          xacc[r][1] = fmaf(av.y, wr[1].y, xacc[r][1]);
          xacc[r][1] = fmaf(av.z, wr[2].y, xacc[r][1]);
          xacc[r][1] = fmaf(av.w, wr[3].y, xacc[r][1]);
          xacc[r][2] = fmaf(av.x, wr[0].z, xacc[r][2]);
          xacc[r][2] = fmaf(av.y, wr[1].z, xacc[r][2]);
          xacc[r][2] = fmaf(av.z, wr[2].z, xacc[r][2]);
          xacc[r][2] = fmaf(av.w, wr[3].z, xacc[r][2]);
          xacc[r][3] = fmaf(av.x, wr[0].w, xacc[r][3]);
          xacc[r][3] = fmaf(av.y, wr[1].w, xacc[r][3]);
          xacc[r][3] = fmaf(av.z, wr[2].w, xacc[r][3]);
          xacc[r][3] = fmaf(av.w, wr[3].w, xacc[r][3]);
        }
      }
    }
    __syncthreads();
  }

  // LN
  if (tid < 512) {
    float b2v[4], gv[4], bv[4];
    #pragma unroll
    for (int q = 0; q < 4; ++q) {
      b2v[q] = b2[ig*4 + q]; gv[q] = lng[ig*4 + q]; bv[q] = lnb[ig*4 + q];
    }
    #pragma unroll
    for (int r = 0; r < 4; ++r) {
      const int row = (tg + 16*r)*HSP + ig*4;
      float4 h0 = *(const float4*)(hs + row);
      float xr[4];
      xr[0] = h0.x + (xacc[r][0] + b2v[0]);
      xr[1] = h0.y + (xacc[r][1] + b2v[1]);
      xr[2] = h0.z + (xacc[r][2] + b2v[2]);
      xr[3] = h0.w + (xacc[r][3] + b2v[3]);
      float s = xr[0] + xr[1] + xr[2] + xr[3];
      s += __shfl_xor(s, 1, 32);  s += __shfl_xor(s, 2, 32);
      s += __shfl_xor(s, 4, 32);  s += __shfl_xor(s, 8, 32);
      s += __shfl_xor(s, 16, 32);
      const float mu = s * 0.0078125f;
      float vs = 0.0f;
      #pragma unroll
      for (int q = 0; q < 4; ++q) { float d = xr[q]-mu; vs = fmaf(d, d, vs); }
      vs += __shfl_xor(vs, 1, 32);  vs += __shfl_xor(vs, 2, 32);
      vs += __shfl_xor(vs, 4, 32);  vs += __shfl_xor(vs, 8, 32);
      vs += __shfl_xor(vs, 16, 32);
      const float rstd = 1.0f / sqrtf(vs * 0.0078125f + C_LNEPS);
      float4 o;
      o.x = (xr[0]-mu)*rstd*gv[0] + bv[0];
      o.y = (xr[1]-mu)*rstd*gv[1] + bv[1];
      o.z = (xr[2]-mu)*rstd*gv[2] + bv[2];
      o.w = (xr[3]-mu)*rstd*gv[3] + bv[3];
      *(float4*)(hs + row) = o;
    }
  }
  __syncthreads();

  // keys = hn @ kp
  {
    float ky[4][4] = {};
    for (int kt = 0; kt < 2; ++kt) {
      if (tid < 512)
        for (int u = tid; u < 64*32; u += 512) {
          const int k = u >> 5, q = u & 31;
          *(float4*)(wt + k*W2P + q*4) =
              *(const float4*)(kp + (long long)(kt*64 + k)*128 + q*4);
        }
      __syncthreads();
      if (tid < 512) {
        #pragma unroll 2
        for (int k4 = 0; k4 < 16; ++k4) {
          float4 wr[4];
          #pragma unroll
          for (int d = 0; d < 4; ++d)
            wr[d] = *(const float4*)(wt + (k4*4 + d)*W2P + ig*4);
          #pragma unroll
          for (int r = 0; r < 4; ++r) {
            float4 hv = *(const float4*)(hs + (tg + 16*r)*HSP + kt*64 + k4*4);
            ky[r][0] = fmaf(hv.x, wr[0].x, ky[r][0]);
            ky[r][0] = fmaf(hv.y, wr[1].x, ky[r][0]);
            ky[r][0] = fmaf(hv.z, wr[2].x, ky[r][0]);
            ky[r][0] = fmaf(hv.w, wr[3].x, ky[r][0]);
            ky[r][1] = fmaf(hv.x, wr[0].y, ky[r][1]);
            ky[r][1] = fmaf(hv.y, wr[1].y, ky[r][1]);
            ky[r][1] = fmaf(hv.z, wr[2].y, ky[r][1]);
            ky[r][1] = fmaf(hv.w, wr[3].y, ky[r][1]);
            ky[r][2] = fmaf(hv.x, wr[0].z, ky[r][2]);
            ky[r][2] = fmaf(hv.y, wr[1].z, ky[r][2]);
            ky[r][2] = fmaf(hv.z, wr[2].z, ky[r][2]);
            ky[r][2] = fmaf(hv.w, wr[3].z, ky[r][2]);
            ky[r][3] = fmaf(hv.x, wr[0].w, ky[r][3]);
            ky[r][3] = fmaf(hv.y, wr[1].w, ky[r][3]);
            ky[r][3] = fmaf(hv.z, wr[2].w, ky[r][3]);
            ky[r][3] = fmaf(hv.w, wr[3].w, ky[r][3]);
          }
        }
      }
      __syncthreads();
    }
    if (tid < 512) {
      #pragma unroll
      for (int r = 0; r < 4; ++r) {
        const long long g = tokBase + tg + 16*r;
        float4 o;
        o.x = ky[r][0]; o.y = ky[r][1]; o.z = ky[r][2]; o.w = ky[r][3];
        *(float4*)(keys + g*HD + ig*4) = o;
      }
    }
  }
}

// ---------------------------------------------------------------------------
// Fused producer/consumer kernel. 256 blocks x 768 threads.
// Blocks 0-63: round-15 scan (identical math) for batch b = blockIdx.x,
//   spin-waiting per-64-token-tile flags before each keys staging read.
// Blocks 64-255: producers; block pb does tiles g = pb + 192k (k=0..5),
//   g = rel*64 + batch (rel-major => early rows first). Publish via
//   __syncthreads + RELEASE flag store (agent scope).
// Deadlock-free: only consumers spin; producers never wait.
// Dynamic LDS = 163328 B (producers use an 86 KB prefix).
// ---------------------------------------------------------------------------
extern "C" __global__ __launch_bounds__(768)
void k_main(const int* __restrict__ seq, const float* __restrict__ embed,
            const float* __restrict__ w1, const float* __restrict__ b1,
            const float* __restrict__ w2, const float* __restrict__ b2,
            const float* __restrict__ lng, const float* __restrict__ lnb,
            const float* __restrict__ kp, float* __restrict__ keys,
            const float* __restrict__ rpw, const float* __restrict__ rpb,
            float* __restrict__ rr, int* flags)
{
  extern __shared__ float sm[];
  const int tid = threadIdx.x;

  if (blockIdx.x >= 64) {
    // ================= producer =================
    const int pb = blockIdx.x - 64;
    for (int k = 0; k < 6; ++k) {
      const int g = pb + 192*k;          // 0..1151
      const int rel = g >> 6, bb2 = g & 63;
      produce_tile(bb2, rel, seq, embed, w1, b1, w2, b2, lng, lnb, kp,
                   keys, sm, tid);
      __syncthreads();
      if (tid == 0)
        __hip_atomic_store(&flags[g], 1, __ATOMIC_RELEASE,
                           __HIP_MEMORY_SCOPE_AGENT);
      __syncthreads();
    }
    return;
  }

  // ================= consumer: the scan =================
  float* Msh  = sm;                    // [128][132]
  float* kbuf = Msh + 128*MSP;         // [3][32][128]
  float* PW   = kbuf + 3*4096;         // [2][32][128]
  float* Gb   = PW + 2*4096;           // [2][32][36]
  float* Gxl  = Gb + 2*32*GPW;         // [32][36] (+inv/tn2)

  const int lane = tid & 63;
  const int w    = tid >> 6;
  const int b    = blockIdx.x;
  const float* kb = keys + (long long)b * LD * HD;

  // ---------------- prologue ----------------
  for (int u = tid; u < 128*MSP; u += NT) Msh[u] = 0.0f;
  for (int u = tid; u < 4096; u += NT) PW[(C0&1)*4096 + u] = 0.0f;
  wait_flag(flags, b);   // tile 0: rows 896..959 (prologue reads 928..959)
  {
    const int b30 = C0 % 3;   // = 2
    for (int u = tid; u < 1024; u += NT)
      *(float4*)(kbuf + b30*4096 + u*4) =
          *(const float4*)(kb + (long long)(C0*32)*HD + u*4);
  }
  __syncthreads();
  {
    const float* kc = kbuf + (C0%3)*4096;
    for (int u = tid; u < 1024; u += NT) {
      const int s = u >> 5, t = u & 31;
      float a = 0.0f;
      for (int j4 = 0; j4 < 32; ++j4) {
        const int col = ((j4 + tid) & 31) * 4;
        float4 sv = *(const float4*)(kc + s*128 + col);
        float4 tv = *(const float4*)(kc + t*128 + col);
        a = fmaf(sv.x,tv.x,a); a = fmaf(sv.y,tv.y,a);
        a = fmaf(sv.z,tv.z,a); a = fmaf(sv.w,tv.w,a);
      }
      Gb[(C0&1)*32*GPW + s*GPW + t] = a;
    }
  }
  if (tid < 256) {
    const int tok = tid >> 3, pp = tid & 7;
    const float* kc = kbuf + (C0%3)*4096;
    float ss = 0.0f;
    #pragma unroll
    for (int q = 0; q < 4; ++q) {
      float4 v = *(const float4*)(kc + tok*128 + pp*16 + q*4);
      ss = fmaf(v.x,v.x,ss); ss = fmaf(v.y,v.y,ss);
      ss = fmaf(v.z,v.z,ss); ss = fmaf(v.w,v.w,ss);
    }
    ss += __shfl_xor(ss,1,8); ss += __shfl_xor(ss,2,8); ss += __shfl_xor(ss,4,8);
    if (pp == 0) {
      const float n = sqrtf(ss);
      INVB(C0&1, tok) = 1.0f / fmaxf(n, C_NEPS);
      const float th = C_THMIN + C_THSPAN * (1.0f - (float)(C0*32 + tok) / 2047.0f);
      const float tn = th * n;
      TN2B(C0&1, tok) = tn * tn;
    }
  }
  __syncthreads();

  // ---------------- main loop ----------------
  for (int c = C0; c <= 64; ++c) {
    const int cur = c & 1, nxt = cur ^ 1;
    const int b3c = c % 3;
    const int b3n = (c + 1) % 3;
    const int b3p = (c + 2) % 3;
    const int t0 = c * 32;

    // wait for the keys tile covering rows t0+32..t0+63
    if (c < 63)
      wait_flag(flags, ((t0 + 63 - 896) >> 6) * 64 + b);

    // ===== phase A =====
    if (w < 8) {
      if (c > C0) {
        const int it = tid >> 5;
        const int jt = tid & 31;
        const int i0 = it*8, j0 = jt*4;
        const float* Wp  = PW + nxt*4096;
        const float* kfp = kbuf + b3p*4096;
        float acc[8][4] = {};
        for (int s = 0; s < 32; ++s) {
          const float4 wa = *(const float4*)(Wp + s*128 + i0);
          const float4 wb = *(const float4*)(Wp + s*128 + i0 + 4);
          const float4 k4 = *(const float4*)(kfp + s*128 + j0);
          float wv[8] = {wa.x,wa.y,wa.z,wa.w,wb.x,wb.y,wb.z,wb.w};
          float kv[4] = {k4.x,k4.y,k4.z,k4.w};
          #pragma unroll
          for (int a = 0; a < 8; ++a)
            #pragma unroll
            for (int q = 0; q < 4; ++q)
              acc[a][q] = fmaf(wv[a], kv[q], acc[a][q]);
        }
        #pragma unroll
        for (int a = 0; a < 8; ++a) {
          float* mp = Msh + (i0 + a)*MSP + j0;
          float4 m = *(float4*)mp;
          m.x = fmaf(C_ALPHA, acc[a][0], m.x);
          m.y = fmaf(C_ALPHA, acc[a][1], m.y);
          m.z = fmaf(C_ALPHA, acc[a][2], m.z);
          m.w = fmaf(C_ALPHA, acc[a][3], m.w);
          *(float4*)mp = m;
        }
      }
    } else {
      const int t2id = tid - 512;
      float4 kvl[4];
      if (c < 63) {
        #pragma unroll
        for (int q = 0; q < 4; ++q)
          kvl[q] = *(const float4*)(kb + (long long)(t0 + 32)*HD + (t2id + 256*q)*4);
      }
      if (c > C0 && c <= 63) {
        const int tt = t2id >> 5;
        const int i0 = (t2id & 31) * 4;
        const int tb4 = tt*4;
        const float* Wp = PW + nxt*4096;
        float fac[4][4] = {};
        for (int s = 0; s < 32; ++s) {
          const float4 gx = *(const float4*)(Gxl + s*GPW + tb4);
          const float4 wp = *(const float4*)(Wp + s*128 + i0);
          float gv[4] = {gx.x,gx.y,gx.z,gx.w};
          float pv[4] = {wp.x,wp.y,wp.z,wp.w};
          #pragma unroll
          for (int a = 0; a < 4; ++a)
            #pragma unroll
            for (int q = 0; q < 4; ++q)
              fac[a][q] = fmaf(gv[a], pv[q], fac[a][q]);
        }
        float* Pp = PW + cur*4096;
        #pragma unroll
        for (int a = 0; a < 4; ++a) {
          float* pp = Pp + (tb4 + a)*128 + i0;
          float4 p = *(float4*)pp;
          p.x = fmaf(C_ALPHA, fac[a][0], p.x);
          p.y = fmaf(C_ALPHA, fac[a][1], p.y);
          p.z = fmaf(C_ALPHA, fac[a][2], p.z);
          p.w = fmaf(C_ALPHA, fac[a][3], p.w);
          *(float4*)pp = p;
        }
      }
      if (c < 63) {
        #pragma unroll
        for (int q = 0; q < 4; ++q)
          *(float4*)(kbuf + b3n*4096 + (t2id + 256*q)*4) = kvl[q];
      }
    }
    __syncthreads();
    if (c == 64) break;

    // ===== phase B (role waves, SIMD-balanced) =====
    if (w == 0) {
      __builtin_amdgcn_s_setprio(1);
      float* Pc = PW + cur*4096;
      const float* kfc = kbuf + b3c*4096;
      const float* Gc  = Gb + cur*32*GPW;
      const int l2 = lane*2;
      float2 acc[16];
      #pragma unroll
      for (int u = 0; u < 16; ++u) { acc[u].x = 0.0f; acc[u].y = 0.0f; }
      #pragma unroll
      for (int t = 0; t < 16; ++t) {
        const float2 p2 = *(const float2*)(Pc + t*128 + l2);
        const float2 k2 = *(const float2*)(kfc + t*128 + l2);
        const float it = INVB(cur, t);
        const float vx = it * fmaf(C_ALPHA, acc[t].x, p2.x);
        const float vy = it * fmaf(C_ALPHA, acc[t].y, p2.y);
        const float ex = k2.x - vx;
        const float ey = k2.y - vy;
        float e2 = fmaf(ex, ex, ey*ey);
        e2 = dpp_add_b1(e2); e2 = dpp_add_4e(e2);
        e2 = dpp_add_hm(e2); e2 = dpp_add_mr(e2);
        e2 = dpp_add_b15(e2); e2 = dpp_add_b31(e2);
        const float en2 = __int_as_float(__builtin_amdgcn_readlane(__float_as_int(e2), 63));
        const bool fire = (en2 >= TN2B(cur, t));
        const float wx = fire ? ex * it : 0.0f;
        const float wy = fire ? ey * it : 0.0f;
        float2 w2v; w2v.x = wx; w2v.y = wy;
        *(float2*)(Pc + t*128 + l2) = w2v;
        const float* gr = Gc + t*GPW;
        #pragma unroll
        for (int u4 = (t+1) & ~3; u4 < 16; u4 += 4) {
          const float4 g = *(const float4*)(gr + u4);
          acc[u4+0].x = fmaf(wx, g.x, acc[u4+0].x); acc[u4+0].y = fmaf(wy, g.x, acc[u4+0].y);
          acc[u4+1].x = fmaf(wx, g.y, acc[u4+1].x); acc[u4+1].y = fmaf(wy, g.y, acc[u4+1].y);
          acc[u4+2].x = fmaf(wx, g.z, acc[u4+2].x); acc[u4+2].y = fmaf(wy, g.z, acc[u4+2].y);
          acc[u4+3].x = fmaf(wx, g.w, acc[u4+3].x); acc[u4+3].y = fmaf(wy, g.w, acc[u4+3].y);
        }
      }
      #pragma unroll
      for (int u = 0; u < 16; ++u) { acc[u].x = 0.0f; acc[u].y = 0.0f; }
      #pragma unroll
      for (int s = 0; s < 16; ++s) {
        const float2 ws = *(const float2*)(Pc + s*128 + l2);
        const float* gs = Gc + s*GPW + 16;
        #pragma unroll
        for (int u4 = 0; u4 < 16; u4 += 4) {
          const float4 g = *(const float4*)(gs + u4);
          acc[u4+0].x = fmaf(ws.x, g.x, acc[u4+0].x); acc[u4+0].y = fmaf(ws.y, g.x, acc[u4+0].y);
          acc[u4+1].x = fmaf(ws.x, g.y, acc[u4+1].x); acc[u4+1].y = fmaf(ws.y, g.y, acc[u4+1].y);
          acc[u4+2].x = fmaf(ws.x, g.z, acc[u4+2].x); acc[u4+2].y = fmaf(ws.y, g.z, acc[u4+2].y);
          acc[u4+3].x = fmaf(ws.x, g.w, acc[u4+3].x); acc[u4+3].y = fmaf(ws.y, g.w, acc[u4+3].y);
        }
      }
      #pragma unroll
      for (int t = 16; t < 32; ++t) {
        const int tt = t - 16;
        const float2 p2 = *(const float2*)(Pc + t*128 + l2);
        const float2 k2 = *(const float2*)(kfc + t*128 + l2);
        const float it = INVB(cur, t);
        const float vx = it * fmaf(C_ALPHA, acc[tt].x, p2.x);
        const float vy = it * fmaf(C_ALPHA, acc[tt].y, p2.y);
        const float ex = k2.x - vx;
        const float ey = k2.y - vy;
        float e2 = fmaf(ex, ex, ey*ey);
        e2 = dpp_add_b1(e2); e2 = dpp_add_4e(e2);
        e2 = dpp_add_hm(e2); e2 = dpp_add_mr(e2);
        e2 = dpp_add_b15(e2); e2 = dpp_add_b31(e2);
        const float en2 = __int_as_float(__builtin_amdgcn_readlane(__float_as_int(e2), 63));
        const bool fire = (en2 >= TN2B(cur, t)) && (t0 + t < NSTEP);
        const float wx = fire ? ex * it : 0.0f;
        const float wy = fire ? ey * it : 0.0f;
        float2 w2v; w2v.x = wx; w2v.y = wy;
        *(float2*)(Pc + t*128 + l2) = w2v;
        const float* gr = Gc + t*GPW + 16;
        #pragma unroll
        for (int u4 = (tt+1) & ~3; u4 < 16; u4 += 4) {
          const float4 g = *(const float4*)(gr + u4);
          acc[u4+0].x = fmaf(wx, g.x, acc[u4+0].x); acc[u4+0].y = fmaf(wy, g.x, acc[u4+0].y);
          acc[u4+1].x = fmaf(wx, g.y, acc[u4+1].x); acc[u4+1].y = fmaf(wy, g.y, acc[u4+1].y);
          acc[u4+2].x = fmaf(wx, g.z, acc[u4+2].x); acc[u4+2].y = fmaf(wy, g.z, acc[u4+2].y);
          acc[u4+3].x = fmaf(wx, g.w, acc[u4+3].x); acc[u4+3].y = fmaf(wy, g.w, acc[u4+3].y);
        }
      }
      __builtin_amdgcn_s_setprio(0);
    } else if (c < 63) {
      int p;
      switch (w) {
        case 4:  p = 0; break;  case 8:  p = 1; break;
        case 1:  p = 2; break;  case 5:  p = 3; break;  case 9:  p = 4; break;
        case 2:  p = 5; break;  case 6:  p = 6; break;  case 10: p = 7; break;
        default: p = -1;
      }
      if (p >= 0) {
        const float* kfn = kbuf + b3n*4096;
        const int tb4 = p*4;
        const int ib = lane & 31, ih = lane >> 5;
        float pa[4][2] = {};
        for (int j4 = 0; j4 < 32; ++j4) {
          float4 kv[4], mv[2];
          #pragma unroll
          for (int ss = 0; ss < 4; ++ss)
            kv[ss] = *(const float4*)(kfn + (tb4+ss)*128 + j4*4);
          #pragma unroll
          for (int r = 0; r < 2; ++r)
            mv[r] = *(const float4*)(Msh + (ib + 32*(ih + 2*r))*MSP + j4*4);
          #pragma unroll
          for (int ss = 0; ss < 4; ++ss)
            #pragma unroll
            for (int r = 0; r < 2; ++r) {
              pa[ss][r] = fmaf(kv[ss].x, mv[r].x, pa[ss][r]);
              pa[ss][r] = fmaf(kv[ss].y, mv[r].y, pa[ss][r]);
              pa[ss][r] = fmaf(kv[ss].z, mv[r].z, pa[ss][r]);
              pa[ss][r] = fmaf(kv[ss].w, mv[r].w, pa[ss][r]);
            }
        }
        float* Pp = PW + nxt*4096;
        #pragma unroll
        for (int ss = 0; ss < 4; ++ss)
          #pragma unroll
          for (int r = 0; r < 2; ++r)
            Pp[(tb4+ss)*128 + ib + 32*(ih + 2*r)] = pa[ss][r];
        if (w == 4) {
          const float* kn = kbuf + b3n*4096;
          const int tok = lane >> 1, hh = lane & 1;
          float ss2 = 0.0f;
          #pragma unroll
          for (int q = 0; q < 16; ++q) {
            const int cq = (q + lane) & 15;
            float4 v = *(const float4*)(kn + tok*128 + hh*64 + cq*4);
            ss2 = fmaf(v.x,v.x,ss2); ss2 = fmaf(v.y,v.y,ss2);
            ss2 = fmaf(v.z,v.z,ss2); ss2 = fmaf(v.w,v.w,ss2);
          }
          ss2 += __shfl_xor(ss2, 1);
          if (hh == 0) {
            const float n = sqrtf(ss2);
            INVB(nxt, tok) = 1.0f / fmaxf(n, C_NEPS);
            const float th = C_THMIN + C_THSPAN * (1.0f - (float)(t0 + 32 + tok) / 2047.0f);
            const float tn = th * n;
            TN2B(nxt, tok) = tn * tn;
          }
        }
      } else if (w == 3) {
        gram_half(kbuf + b3n*4096, kbuf + b3n*4096, Gb + nxt*32*GPW, 0, lane);
      } else if (w == 7) {
        gram_half(kbuf + b3n*4096, kbuf + b3n*4096, Gb + nxt*32*GPW, 1, lane);
      } else {
        gram_half(kbuf + b3c*4096, kbuf + b3n*4096, Gxl, 0, lane);
        gram_half(kbuf + b3c*4096, kbuf + b3n*4096, Gxl, 1, lane);
      }
    }
    __syncthreads();
  }

  // ---------------- fused k_read epilogue ----------------
  {
    float* qv = PW;          // reuse [128]
    float* rd = PW + 128;    // reuse [128]
    if (tid < 32)
      *(float4*)(qv + tid*4) =
          *(const float4*)(kb + (long long)(LD-1)*HD + tid*4);
    __syncthreads();
    if (tid < 512) {
      const int i = tid >> 2, p = tid & 3;
      const float* mr = Msh + i*MSP + p*32;
      const float* qp = qv + p*32;
      float a0 = 0.0f, a1 = 0.0f;
      #pragma unroll
      for (int q4 = 0; q4 < 8; q4 += 2) {
        const float4 m0 = *(const float4*)(mr + q4*4);
        const float4 m1 = *(const float4*)(mr + q4*4 + 4);
        a0 = fmaf(m0.x, qp[q4*4+0], a0); a0 = fmaf(m0.y, qp[q4*4+1], a0);
        a0 = fmaf(m0.z, qp[q4*4+2], a0); a0 = fmaf(m0.w, qp[q4*4+3], a0);
        a1 = fmaf(m1.x, qp[q4*4+4], a1); a1 = fmaf(m1.y, qp[q4*4+5], a1);
        a1 = fmaf(m1.z, qp[q4*4+6], a1); a1 = fmaf(m1.w, qp[q4*4+7], a1);
      }
      float acc = a0 + a1;
      acc += __shfl_xor(acc, 1);
      acc += __shfl_xor(acc, 2);
      if (p == 0) rd[i] = acc;
    }
    __syncthreads();
    if (tid < 128) {
      float s0 = rpb[tid], s1 = 0.0f, s2 = 0.0f, s3 = 0.0f;
      for (int k = 0; k < 128; k += 4) {
        s0 = fmaf(rd[k+0], rpw[(k+0)*128 + tid], s0);
        s1 = fmaf(rd[k+1], rpw[(k+1)*128 + tid], s1);
        s2 = fmaf(rd[k+2], rpw[(k+2)*128 + tid], s2);
        s3 = fmaf(rd[k+3], rpw[(k+3)*128 + tid], s3);
      }
      rr[b*128 + tid] = (s0 + s1) + (s2 + s3);
    }
  }
}

// ---------------------------------------------------------------------------
// K4b: out[b][v] = rr[b] . out_w[:,v] + out_b[v]  (round-14 exact)
// ---------------------------------------------------------------------------
extern "C" __global__ __launch_bounds__(256, 1)
void k_out(const float* __restrict__ rr, const float* __restrict__ outw,
           const float* __restrict__ outb, float* __restrict__ out)
{
  __shared__ float rl[64*128];
  const int tid = threadIdx.x;
  for (int u = tid; u < 8192; u += 256) rl[u] = rr[u];
  __syncthreads();
  const int v  = blockIdx.x*64 + (tid & 63);
  const int bg = tid >> 6;
  const float ob = outb[v];
  const float* rbase = rl + bg*16*128;
  float acc[16];
  #pragma unroll
  for (int bb = 0; bb < 16; ++bb) acc[bb] = 0.0f;
  for (int h = 0; h < 128; h += 2) {
    const float wv0 = outw[(long long)h*VD + v];
    const float wv1 = outw[(long long)(h+1)*VD + v];
    #pragma unroll
    for (int bb = 0; bb < 16; ++bb) {
      acc[bb] = fmaf(rbase[bb*128 + h],     wv0, acc[bb]);
      acc[bb] = fmaf(rbase[bb*128 + h + 1], wv1, acc[bb]);
    }
  }
  #pragma unroll
  for (int bb = 0; bb < 16; ++bb)
    out[(long long)(bg*16 + bb)*VD + v] = acc[bb] + ob;
}

// ---------------------------------------------------------------------------
extern "C" void kernel_launch(void* const* d_in, const int* in_sizes, int n_in,
                              void* d_out, int out_size, void* d_ws, size_t ws_size,
                              hipStream_t stream)
{
  const int*   seq   = (const int*)d_in[0];
  const float* embed = (const float*)d_in[1];
  const float* w1    = (const float*)d_in[2];
  const float* b1    = (const float*)d_in[3];
  const float* w2    = (const float*)d_in[4];
  const float* b2    = (const float*)d_in[5];
  const float* ln_g  = (const float*)d_in[6];
  const float* ln_b  = (const float*)d_in[7];
  const float* kp_w  = (const float*)d_in[8];
  const float* rp_w  = (const float*)d_in[9];
  const float* rp_b  = (const float*)d_in[10];
  const float* out_w = (const float*)d_in[11];
  const float* out_b = (const float*)d_in[12];
  float* out = (float*)d_out;

  char* ws = (char*)d_ws;
  float* keys = (float*)ws;                               // 64 MiB
  float* rr   = (float*)(ws + 67108864 + 4194304);        // 32 KiB
  int*   flags = (int*)(ws + 67108864 + 4194304 + 65536); // 1152 ints

  hipMemsetAsync(flags, 0, 1152 * sizeof(int), stream);
  hipLaunchKernelGGL(k_main, dim3(256), dim3(768), 163328, stream,
                     seq, embed, w1, b1, w2, b2, ln_g, ln_b, kp_w,
                     keys, rp_w, rp_b, rr, flags);
  hipLaunchKernelGGL(k_out, dim3(500), dim3(256), 0, stream, rr, out_w, out_b, out);
}